// Round 1
// baseline (695.171 us; speedup 1.0000x reference)
//
#include <hip/hip_runtime.h>

#define T_TOK 16384
#define DIM 768
#define NEXP 4
#define DFF_ 1024

typedef __attribute__((ext_vector_type(4))) float f32x4;
typedef __attribute__((ext_vector_type(8))) short s16x8;

__device__ __forceinline__ unsigned short f32_to_bf16(float f) {
  unsigned int u = __float_as_uint(f);
  unsigned int r = (u + 0x7FFFu + ((u >> 16) & 1u)) >> 16;  // RNE
  return (unsigned short)r;
}

// ---------- transpose fp32 [R,C] -> bf16 [C,R] (batched over z) ----------
__global__ void transpose_bf16_kernel(const float* __restrict__ in,
                                      unsigned short* __restrict__ out,
                                      int R, int C) {
  __shared__ float tile[32][33];
  const int bx = blockIdx.x, by = blockIdx.y, bz = blockIdx.z;
  in  += (size_t)bz * R * C;
  out += (size_t)bz * R * C;
  const int tx = threadIdx.x, ty = threadIdx.y;
#pragma unroll
  for (int i = 0; i < 4; i++) {
    int r = by * 32 + ty + i * 8;
    int c = bx * 32 + tx;
    tile[ty + i * 8][tx] = in[(size_t)r * C + c];
  }
  __syncthreads();
#pragma unroll
  for (int i = 0; i < 4; i++) {
    int oc = bx * 32 + ty + i * 8;  // out row (= in col)
    int orow = by * 32 + tx;        // out col (= in row)
    out[(size_t)oc * R + orow] = f32_to_bf16(tile[tx][ty + i * 8]);
  }
}

// ---------- fp32 -> bf16 straight copy, 8 elems/thread ----------
__global__ void convert_bf16_kernel(const float* __restrict__ in,
                                    unsigned short* __restrict__ out) {
  size_t i = ((size_t)blockIdx.x * 256 + threadIdx.x) * 8;
  float4 a = *(const float4*)(in + i);
  float4 b = *(const float4*)(in + i + 4);
  union { unsigned short u[8]; uint4 v; } pk;
  pk.u[0] = f32_to_bf16(a.x); pk.u[1] = f32_to_bf16(a.y);
  pk.u[2] = f32_to_bf16(a.z); pk.u[3] = f32_to_bf16(a.w);
  pk.u[4] = f32_to_bf16(b.x); pk.u[5] = f32_to_bf16(b.y);
  pk.u[6] = f32_to_bf16(b.z); pk.u[7] = f32_to_bf16(b.w);
  *(uint4*)(out + i) = pk.v;
}

// ---------- Wfg = W @ Wg  [DIM,NEXP], bgp = b @ Wg + bg  (fp32) ----------
__global__ void wfg_kernel(const float* __restrict__ W, const float* __restrict__ Wg,
                           const float* __restrict__ b, const float* __restrict__ bg,
                           float* __restrict__ wfg, float* __restrict__ bgp) {
  int gid = blockIdx.x * 256 + threadIdx.x;
  if (gid < DIM * NEXP) {
    int k = gid >> 2, e = gid & 3;
    const float* wr = W + (size_t)k * DIM;
    float acc = 0.f;
    for (int d = 0; d < DIM; d++) acc += wr[d] * Wg[d * NEXP + e];
    wfg[gid] = acc;  // layout [k][e]
  } else if (gid < DIM * NEXP + NEXP) {
    int e = gid - DIM * NEXP;
    float acc = bg[e];
    for (int d = 0; d < DIM; d++) acc += b[d] * Wg[d * NEXP + e];
    bgp[e] = acc;
  }
}

// ---------- router: fp32 logits = x@Wfg + bgp, softmax, top2, gates ----------
// Also initializes out[t,:] = sum_e comb[t,e] * b2[e,:]
__global__ void router_kernel(const float* __restrict__ x, const float* __restrict__ wfg,
                              const float* __restrict__ bgp, const float* __restrict__ b2,
                              float* __restrict__ comb, float* __restrict__ out) {
  __shared__ float wfgS[DIM * NEXP];
  __shared__ float b2S[NEXP * DIM];
  const int tid = threadIdx.x;
  for (int i = tid; i < DIM * NEXP; i += 256) { wfgS[i] = wfg[i]; b2S[i] = b2[i]; }
  __syncthreads();
  const int w = tid >> 6, lane = tid & 63;
  const size_t t = (size_t)blockIdx.x * 4 + w;
  const float* xr = x + t * DIM;
  float a0 = 0.f, a1 = 0.f, a2 = 0.f, a3 = 0.f;
#pragma unroll
  for (int i = 0; i < 12; i++) {
    int k = i * 64 + lane;
    float xv = xr[k];
    a0 += xv * wfgS[k * 4 + 0];
    a1 += xv * wfgS[k * 4 + 1];
    a2 += xv * wfgS[k * 4 + 2];
    a3 += xv * wfgS[k * 4 + 3];
  }
#pragma unroll
  for (int off = 32; off > 0; off >>= 1) {
    a0 += __shfl_xor(a0, off);
    a1 += __shfl_xor(a1, off);
    a2 += __shfl_xor(a2, off);
    a3 += __shfl_xor(a3, off);
  }
  float l[NEXP] = {a0 + bgp[0], a1 + bgp[1], a2 + bgp[2], a3 + bgp[3]};
  float m = fmaxf(fmaxf(l[0], l[1]), fmaxf(l[2], l[3]));
  float p[NEXP]; float s = 0.f;
#pragma unroll
  for (int e = 0; e < NEXP; e++) { p[e] = expf(l[e] - m); s += p[e]; }
#pragma unroll
  for (int e = 0; e < NEXP; e++) p[e] /= s;
  int i1 = 0;
#pragma unroll
  for (int e = 1; e < NEXP; e++) if (p[e] > p[i1]) i1 = e;  // ties -> lowest idx (matches top_k)
  int i2 = -1;
#pragma unroll
  for (int e = 0; e < NEXP; e++) { if (e == i1) continue; if (i2 < 0 || p[e] > p[i2]) i2 = e; }
  float denom = p[i1] + p[i2];
  float c[NEXP] = {0.f, 0.f, 0.f, 0.f};
  c[i1] = p[i1] / denom;
  c[i2] = p[i2] / denom;
  if (lane < NEXP) comb[t * NEXP + lane] = c[lane];
#pragma unroll
  for (int i = 0; i < 12; i++) {
    int n = i * 64 + lane;
    out[t * DIM + n] = c[0] * b2S[n] + c[1] * b2S[DIM + n] + c[2] * b2S[2 * DIM + n] + c[3] * b2S[3 * DIM + n];
  }
}

// ---------- m97-class bf16 GEMM: C[M,N] = A[M,K] @ Bt[N,K]^T ----------
// MODE 0: store bf16(acc + bias[col])                (GEMM1 -> t)
// MODE 1: store bf16(comb[row]*gelu(acc+bias[col]))  (GEMM2 -> g)
// MODE 2: outF[row,col] += acc                       (GEMM3 -> out, fp32 RMW)
template <int MODE>
__launch_bounds__(256)
__global__ void gemm_kernel(const unsigned short* __restrict__ A,
                            const unsigned short* __restrict__ Bt,
                            const int K, const int N,
                            const float* __restrict__ bias,
                            const float* __restrict__ comb, const int expert,
                            unsigned short* __restrict__ outB,
                            float* __restrict__ outF) {
  __shared__ unsigned short As[128 * 32];  // [row][k], 64B rows
  __shared__ unsigned short Bs[128 * 32];  // [n][k]
  __shared__ float combS[128];

  const int tid = threadIdx.x;
  const int w = tid >> 6;
  const int lane = tid & 63;
  const int bm0 = blockIdx.y * 128;
  const int bn0 = blockIdx.x * 128;

  if constexpr (MODE == 1) {
    if (tid < 128) combS[tid] = comb[(size_t)(bm0 + tid) * NEXP + expert];
  }

  f32x4 acc[4][4];
#pragma unroll
  for (int i = 0; i < 4; i++)
#pragma unroll
    for (int j = 0; j < 4; j++) acc[i][j] = (f32x4){0.f, 0.f, 0.f, 0.f};

  const int quad = lane >> 4;
  const int m16 = lane & 15;
  const int wm = (w & 1) * 64;
  const int wn = (w >> 1) * 64;

  for (int k0 = 0; k0 < K; k0 += 32) {
#pragma unroll
    for (int s = 0; s < 2; s++) {
      int o = s * 4096 + tid * 16;          // byte offset in 8KB tile
      int row = o >> 6;                     // 64B per row of 32 bf16
      int kof = (o & 63) >> 1;
      const unsigned short* ga = A + (size_t)(bm0 + row) * K + k0 + kof;
      const unsigned short* gb = Bt + (size_t)(bn0 + row) * K + k0 + kof;
      char* la = (char*)As + s * 4096 + w * 1024;  // wave-uniform base + lane*16
      char* lb = (char*)Bs + s * 4096 + w * 1024;
      __builtin_amdgcn_global_load_lds((const __attribute__((address_space(1))) void*)ga,
                                       (__attribute__((address_space(3))) void*)la, 16, 0, 0);
      __builtin_amdgcn_global_load_lds((const __attribute__((address_space(1))) void*)gb,
                                       (__attribute__((address_space(3))) void*)lb, 16, 0, 0);
    }
    __syncthreads();
    s16x8 af[4], bf[4];
#pragma unroll
    for (int i = 0; i < 4; i++)
      af[i] = *(const s16x8*)((const char*)As + (wm + i * 16 + m16) * 64 + quad * 16);
#pragma unroll
    for (int j = 0; j < 4; j++)
      bf[j] = *(const s16x8*)((const char*)Bs + (wn + j * 16 + m16) * 64 + quad * 16);
#pragma unroll
    for (int i = 0; i < 4; i++)
#pragma unroll
      for (int j = 0; j < 4; j++)
        acc[i][j] = __builtin_amdgcn_mfma_f32_16x16x32_bf16(af[i], bf[j], acc[i][j], 0, 0, 0);
    __syncthreads();
  }

#pragma unroll
  for (int i = 0; i < 4; i++) {
    const int rbase = bm0 + wm + i * 16 + quad * 4;
    const int rloc = wm + i * 16 + quad * 4;
#pragma unroll
    for (int j = 0; j < 4; j++) {
      const int col = bn0 + wn + j * 16 + m16;
      if constexpr (MODE == 0) {
        float bv = bias[col];
#pragma unroll
        for (int r = 0; r < 4; r++)
          outB[(size_t)(rbase + r) * N + col] = f32_to_bf16(acc[i][j][r] + bv);
      } else if constexpr (MODE == 1) {
        float bv = bias[col];
#pragma unroll
        for (int r = 0; r < 4; r++) {
          float v = acc[i][j][r] + bv;
          // tanh-approx gelu (JAX default)
          float u = 0.7978845608028654f * (v + 0.044715f * v * v * v);
          float e2 = exp2f(u * 2.8853900817779268f);  // e^{2u}
          float th = 1.0f - 2.0f / (1.0f + e2);
          float g = 0.5f * v * (1.0f + th);
          outB[(size_t)(rbase + r) * N + col] = f32_to_bf16(g * combS[rloc + r]);
        }
      } else {
#pragma unroll
        for (int r = 0; r < 4; r++) {
          size_t o = (size_t)(rbase + r) * N + col;
          outF[o] += acc[i][j][r];
        }
      }
    }
  }
}

extern "C" void kernel_launch(void* const* d_in, const int* in_sizes, int n_in,
                              void* d_out, int out_size, void* d_ws, size_t ws_size,
                              hipStream_t stream) {
  (void)in_sizes; (void)n_in; (void)out_size; (void)ws_size;
  const float* x  = (const float*)d_in[0];
  const float* W  = (const float*)d_in[1];
  const float* b  = (const float*)d_in[2];
  const float* Wg = (const float*)d_in[3];
  const float* bg = (const float*)d_in[4];
  const float* W1 = (const float*)d_in[5];
  const float* b1 = (const float*)d_in[6];
  const float* W2 = (const float*)d_in[7];
  const float* b2 = (const float*)d_in[8];
  float* out = (float*)d_out;
  char* ws = (char*)d_ws;

  // workspace layout (bytes, 256-aligned)
  unsigned short* xbf  = (unsigned short*)(ws + 0);          // 16384*768 bf16
  unsigned short* tbf  = (unsigned short*)(ws + 25165824);   // 16384*768 bf16
  unsigned short* wt   = (unsigned short*)(ws + 50331648);   // W^T   [768][768]
  unsigned short* w1t  = (unsigned short*)(ws + 51511296);   // W1^T  [4][1024][768]
  unsigned short* w2t  = (unsigned short*)(ws + 57802752);   // W2^T  [4][768][1024]
  float* comb          = (float*)(ws + 64094208);            // [16384][4]
  float* wfg           = (float*)(ws + 64356352);            // [768][4]
  float* bgp           = (float*)(ws + 64368640);            // [4]
  unsigned short* gbuf = (unsigned short*)(ws + 64368896);   // [16384][1024] bf16 (per-expert reuse)

  transpose_bf16_kernel<<<dim3(24, 24, 1), dim3(32, 8), 0, stream>>>(W, wt, 768, 768);
  transpose_bf16_kernel<<<dim3(32, 24, 4), dim3(32, 8), 0, stream>>>(W1, w1t, 768, 1024);
  transpose_bf16_kernel<<<dim3(24, 32, 4), dim3(32, 8), 0, stream>>>(W2, w2t, 1024, 768);
  convert_bf16_kernel<<<6144, 256, 0, stream>>>(x, xbf);
  wfg_kernel<<<13, 256, 0, stream>>>(W, Wg, b, bg, wfg, bgp);
  router_kernel<<<4096, 256, 0, stream>>>(x, wfg, bgp, b2, comb, out);

  // t = bf16(x @ W + b)
  gemm_kernel<0><<<dim3(6, 128), 256, 0, stream>>>(xbf, wt, 768, 768, b, nullptr, 0, tbf, nullptr);

  for (int e = 0; e < NEXP; e++) {
    // g = bf16(comb_e * gelu(t @ W1_e + b1_e))
    gemm_kernel<1><<<dim3(8, 128), 256, 0, stream>>>(tbf, w1t + (size_t)e * DFF_ * DIM, 768, 1024,
                                                     b1 + e * DFF_, comb, e, gbuf, nullptr);
    // out += g @ W2_e
    gemm_kernel<2><<<dim3(6, 128), 256, 0, stream>>>(gbuf, w2t + (size_t)e * DIM * DFF_, 1024, 768,
                                                     nullptr, nullptr, 0, nullptr, out);
  }
}

// Round 2
// 610.385 us; speedup vs baseline: 1.1389x; 1.1389x over previous
//
#include <hip/hip_runtime.h>

#define T_TOK 16384
#define DIM 768
#define NEXP 4
#define DFF_ 1024

typedef __attribute__((ext_vector_type(4))) float f32x4;
typedef __attribute__((ext_vector_type(8))) short s16x8;

__device__ __forceinline__ unsigned short f32_to_bf16(float f) {
  unsigned int u = __float_as_uint(f);
  unsigned int r = (u + 0x7FFFu + ((u >> 16) & 1u)) >> 16;  // RNE
  return (unsigned short)r;
}

// ---------- transpose fp32 [R,C] -> bf16, generalized output addressing ----------
// out[z*zOut + oc*ldo + orow] = in[z*R*C + orow*C + oc]
__global__ void transpose_bf16_kernel(const float* __restrict__ in,
                                      unsigned short* __restrict__ out,
                                      int R, int C, int ldo, int zOut) {
  __shared__ float tile[32][33];
  const int bx = blockIdx.x, by = blockIdx.y, bz = blockIdx.z;
  in  += (size_t)bz * R * C;
  out += (size_t)bz * zOut;
  const int tx = threadIdx.x, ty = threadIdx.y;
#pragma unroll
  for (int i = 0; i < 4; i++) {
    int r = by * 32 + ty + i * 8;
    int c = bx * 32 + tx;
    tile[ty + i * 8][tx] = in[(size_t)r * C + c];
  }
  __syncthreads();
#pragma unroll
  for (int i = 0; i < 4; i++) {
    int oc = bx * 32 + ty + i * 8;  // out row (= in col)
    int orow = by * 32 + tx;        // out col (= in row)
    out[(size_t)oc * ldo + orow] = f32_to_bf16(tile[tx][ty + i * 8]);
  }
}

// ---------- fp32 -> bf16 straight copy, 8 elems/thread ----------
__global__ void convert_bf16_kernel(const float* __restrict__ in,
                                    unsigned short* __restrict__ out) {
  size_t i = ((size_t)blockIdx.x * 256 + threadIdx.x) * 8;
  float4 a = *(const float4*)(in + i);
  float4 b = *(const float4*)(in + i + 4);
  union { unsigned short u[8]; uint4 v; } pk;
  pk.u[0] = f32_to_bf16(a.x); pk.u[1] = f32_to_bf16(a.y);
  pk.u[2] = f32_to_bf16(a.z); pk.u[3] = f32_to_bf16(a.w);
  pk.u[4] = f32_to_bf16(b.x); pk.u[5] = f32_to_bf16(b.y);
  pk.u[6] = f32_to_bf16(b.z); pk.u[7] = f32_to_bf16(b.w);
  *(uint4*)(out + i) = pk.v;
}

// ---------- Wfg = W @ Wg  [DIM,NEXP], bgp = b @ Wg + bg  (fp32) ----------
__global__ void wfg_kernel(const float* __restrict__ W, const float* __restrict__ Wg,
                           const float* __restrict__ b, const float* __restrict__ bg,
                           float* __restrict__ wfg, float* __restrict__ bgp) {
  int gid = blockIdx.x * 256 + threadIdx.x;
  if (gid < DIM * NEXP) {
    int k = gid >> 2, e = gid & 3;
    const float* wr = W + (size_t)k * DIM;
    float acc = 0.f;
    for (int d = 0; d < DIM; d++) acc += wr[d] * Wg[d * NEXP + e];
    wfg[gid] = acc;  // layout [k][e]
  } else if (gid < DIM * NEXP + NEXP) {
    int e = gid - DIM * NEXP;
    float acc = bg[e];
    for (int d = 0; d < DIM; d++) acc += b[d] * Wg[d * NEXP + e];
    bgp[e] = acc;
  }
}

// ---------- router: fp32 logits = x@Wfg + bgp, softmax, top2, gates ----------
__global__ void router_kernel(const float* __restrict__ x, const float* __restrict__ wfg,
                              const float* __restrict__ bgp,
                              float* __restrict__ comb) {
  __shared__ float wfgS[DIM * NEXP];
  const int tid = threadIdx.x;
  for (int i = tid; i < DIM * NEXP; i += 256) wfgS[i] = wfg[i];
  __syncthreads();
  const int w = tid >> 6, lane = tid & 63;
  const size_t t = (size_t)blockIdx.x * 4 + w;
  const float* xr = x + t * DIM;
  float a0 = 0.f, a1 = 0.f, a2 = 0.f, a3 = 0.f;
#pragma unroll
  for (int i = 0; i < 12; i++) {
    int k = i * 64 + lane;
    float xv = xr[k];
    a0 += xv * wfgS[k * 4 + 0];
    a1 += xv * wfgS[k * 4 + 1];
    a2 += xv * wfgS[k * 4 + 2];
    a3 += xv * wfgS[k * 4 + 3];
  }
#pragma unroll
  for (int off = 32; off > 0; off >>= 1) {
    a0 += __shfl_xor(a0, off);
    a1 += __shfl_xor(a1, off);
    a2 += __shfl_xor(a2, off);
    a3 += __shfl_xor(a3, off);
  }
  float l[NEXP] = {a0 + bgp[0], a1 + bgp[1], a2 + bgp[2], a3 + bgp[3]};
  float m = fmaxf(fmaxf(l[0], l[1]), fmaxf(l[2], l[3]));
  float p[NEXP]; float s = 0.f;
#pragma unroll
  for (int e = 0; e < NEXP; e++) { p[e] = expf(l[e] - m); s += p[e]; }
#pragma unroll
  for (int e = 0; e < NEXP; e++) p[e] /= s;
  int i1 = 0;
#pragma unroll
  for (int e = 1; e < NEXP; e++) if (p[e] > p[i1]) i1 = e;  // ties -> lowest idx
  int i2 = -1;
#pragma unroll
  for (int e = 0; e < NEXP; e++) { if (e == i1) continue; if (i2 < 0 || p[e] > p[i2]) i2 = e; }
  float denom = p[i1] + p[i2];
  float c[NEXP] = {0.f, 0.f, 0.f, 0.f};
  c[i1] = p[i1] / denom;
  c[i2] = p[i2] / denom;
  if (lane < NEXP) comb[t * NEXP + lane] = c[lane];
}

// ---------- m97-class bf16 GEMM: C[M,N] = A[M,K] @ Bt[N,K]^T ----------
// LDS staging uses a quad XOR swizzle (gq = sq ^ (row&3)) to cut fragment-read
// bank conflicts from 8-way to 4-way; the swizzle is realized on the GLOBAL
// address side since global_load_lds scatters lane-contiguously in LDS.
// MODE 0: outB = bf16(acc + bias[col])                       (GEMM1 -> t)
// MODE 1: outB = bf16(comb[row,e]*gelu(acc+bias[col]))       (GEMM2 -> g), e = expert>=0?expert:bn0>>10
// MODE 2: outF = acc + sum_e comb[row,e]*b2[e,col]  (write-once, GEMM3)
// MODE 3: outF += acc                                (RMW, fallback GEMM3 e>0)
template <int MODE>
__launch_bounds__(256)
__global__ void gemm_kernel(const unsigned short* __restrict__ A, const int lda,
                            const unsigned short* __restrict__ Bt, const int ldb,
                            const int K, const int N,
                            const float* __restrict__ bias,
                            const float* __restrict__ comb, const int expert,
                            const float* __restrict__ b2,
                            unsigned short* __restrict__ outB,
                            float* __restrict__ outF, const int ldo) {
  __shared__ unsigned short As[128 * 32];  // [row][k] 64B rows, quad-swizzled
  __shared__ unsigned short Bs[128 * 32];
  __shared__ float combS[128];
  __shared__ float4 combS4[128];
  __shared__ float b2S[NEXP * 128];

  const int tid = threadIdx.x;
  const int w = tid >> 6;
  const int lane = tid & 63;
  const int bm0 = blockIdx.y * 128;
  const int bn0 = blockIdx.x * 128;

  if constexpr (MODE == 1) {
    const int eIdx = (expert >= 0) ? expert : (bn0 >> 10);
    if (tid < 128) combS[tid] = comb[(size_t)(bm0 + tid) * NEXP + eIdx];
  }
  if constexpr (MODE == 2) {
    if (tid < 128) combS4[tid] = ((const float4*)comb)[bm0 + tid];
    for (int i = tid; i < NEXP * 128; i += 256) {
      int e = i >> 7, c = i & 127;
      b2S[i] = b2[e * DIM + bn0 + c];
    }
  }

  f32x4 acc[4][4];
#pragma unroll
  for (int i = 0; i < 4; i++)
#pragma unroll
    for (int j = 0; j < 4; j++) acc[i][j] = (f32x4){0.f, 0.f, 0.f, 0.f};

  const int quad = lane >> 4;
  const int m16 = lane & 15;
  const int wm = (w & 1) * 64;
  const int wn = (w >> 1) * 64;

  for (int k0 = 0; k0 < K; k0 += 32) {
#pragma unroll
    for (int s = 0; s < 2; s++) {
      int Lb = s * 256 + tid;         // 16B-block index within 8KB tile
      int row = Lb >> 2;
      int sq = Lb & 3;
      int gq = sq ^ (row & 3);        // which global quad lands in this slot
      const unsigned short* ga = A + (size_t)(bm0 + row) * lda + k0 + gq * 8;
      const unsigned short* gb = Bt + (size_t)(bn0 + row) * ldb + k0 + gq * 8;
      char* la = (char*)As + s * 4096 + w * 1024;  // wave-uniform base (+lane*16 by HW)
      char* lb = (char*)Bs + s * 4096 + w * 1024;
      __builtin_amdgcn_global_load_lds((const __attribute__((address_space(1))) void*)ga,
                                       (__attribute__((address_space(3))) void*)la, 16, 0, 0);
      __builtin_amdgcn_global_load_lds((const __attribute__((address_space(1))) void*)gb,
                                       (__attribute__((address_space(3))) void*)lb, 16, 0, 0);
    }
    __syncthreads();
    const int sw = (quad ^ (m16 & 3)) * 16;  // de-swizzle on the read side
    s16x8 af[4], bf[4];
#pragma unroll
    for (int i = 0; i < 4; i++)
      af[i] = *(const s16x8*)((const char*)As + (wm + i * 16 + m16) * 64 + sw);
#pragma unroll
    for (int j = 0; j < 4; j++)
      bf[j] = *(const s16x8*)((const char*)Bs + (wn + j * 16 + m16) * 64 + sw);
#pragma unroll
    for (int i = 0; i < 4; i++)
#pragma unroll
      for (int j = 0; j < 4; j++)
        acc[i][j] = __builtin_amdgcn_mfma_f32_16x16x32_bf16(af[i], bf[j], acc[i][j], 0, 0, 0);
    __syncthreads();
  }

#pragma unroll
  for (int i = 0; i < 4; i++) {
    const int rbase = bm0 + wm + i * 16 + quad * 4;
    const int rloc = wm + i * 16 + quad * 4;
#pragma unroll
    for (int j = 0; j < 4; j++) {
      const int col = bn0 + wn + j * 16 + m16;
      const int cloc = wn + j * 16 + m16;
      if constexpr (MODE == 0) {
        float bv = bias[col];
#pragma unroll
        for (int r = 0; r < 4; r++)
          outB[(size_t)(rbase + r) * ldo + col] = f32_to_bf16(acc[i][j][r] + bv);
      } else if constexpr (MODE == 1) {
        float bv = bias[col];
#pragma unroll
        for (int r = 0; r < 4; r++) {
          float v = acc[i][j][r] + bv;
          // tanh-approx gelu: g = v*(1 - 1/(1+e^{2u})), u = sqrt(2/pi)(v+0.044715v^3)
          float t3 = v + 0.044715f * v * v * v;
          float e2 = exp2f(t3 * 2.302208206984525f);  // e^{2u}
          float rc = __builtin_amdgcn_rcpf(1.0f + e2);
          float g = v - v * rc;
          outB[(size_t)(rbase + r) * ldo + col] = f32_to_bf16(g * combS[rloc + r]);
        }
      } else if constexpr (MODE == 2) {
        float bx = b2S[cloc], by = b2S[128 + cloc], bz = b2S[256 + cloc], bw = b2S[384 + cloc];
#pragma unroll
        for (int r = 0; r < 4; r++) {
          float4 cb = combS4[rloc + r];
          float base = cb.x * bx + cb.y * by + cb.z * bz + cb.w * bw;
          outF[(size_t)(rbase + r) * ldo + col] = acc[i][j][r] + base;
        }
      } else {
#pragma unroll
        for (int r = 0; r < 4; r++) {
          size_t o = (size_t)(rbase + r) * ldo + col;
          outF[o] += acc[i][j][r];
        }
      }
    }
  }
}

extern "C" void kernel_launch(void* const* d_in, const int* in_sizes, int n_in,
                              void* d_out, int out_size, void* d_ws, size_t ws_size,
                              hipStream_t stream) {
  (void)in_sizes; (void)n_in; (void)out_size;
  const float* x  = (const float*)d_in[0];
  const float* W  = (const float*)d_in[1];
  const float* b  = (const float*)d_in[2];
  const float* Wg = (const float*)d_in[3];
  const float* bg = (const float*)d_in[4];
  const float* W1 = (const float*)d_in[5];
  const float* b1 = (const float*)d_in[6];
  const float* W2 = (const float*)d_in[7];
  const float* b2 = (const float*)d_in[8];
  float* out = (float*)d_out;
  char* ws = (char*)d_ws;

  // workspace layout (bytes)
  unsigned short* tbf  = (unsigned short*)(ws + 0);          // [16384][768] bf16
  unsigned short* wt   = (unsigned short*)(ws + 25165824);   // W^T   [768][768]
  unsigned short* w1t  = (unsigned short*)(ws + 26345472);   // W1^T  [4][1024][768] = [4096][768]
  unsigned short* w2t2 = (unsigned short*)(ws + 32636928);   // W2 concat-T [768][4096]
  float* comb          = (float*)(ws + 38928384);            // [16384][4]
  float* wfg           = (float*)(ws + 39190528);            // [768][4]
  float* bgp           = (float*)(ws + 39202816);            // [4]
  unsigned short* xbf  = (unsigned short*)(ws + 39203072);   // [16384][768] bf16
  unsigned short* gall = (unsigned short*)(ws + 64368896);   // [16384][4096] bf16 (merged path)
  unsigned short* gbuf = gall;                               // [16384][1024] (fallback, reused)

  const bool merged = ws_size >= (64368896ULL + 134217728ULL);

  transpose_bf16_kernel<<<dim3(24, 24, 1), dim3(32, 8), 0, stream>>>(W, wt, 768, 768, 768, 589824);
  transpose_bf16_kernel<<<dim3(32, 24, 4), dim3(32, 8), 0, stream>>>(W1, w1t, 768, 1024, 768, 786432);
  transpose_bf16_kernel<<<dim3(24, 32, 4), dim3(32, 8), 0, stream>>>(W2, w2t2, 1024, 768, 4096, 1024);
  convert_bf16_kernel<<<6144, 256, 0, stream>>>(x, xbf);
  wfg_kernel<<<13, 256, 0, stream>>>(W, Wg, b, bg, wfg, bgp);
  router_kernel<<<4096, 256, 0, stream>>>(x, wfg, bgp, comb);

  // GEMM1: t = bf16(x @ W + b)
  gemm_kernel<0><<<dim3(6, 128), 256, 0, stream>>>(xbf, 768, wt, 768, 768, 768,
                                                   b, nullptr, 0, nullptr, tbf, nullptr, 768);

  if (merged) {
    // GEMM2 (all experts): gall[:, e*1024+f] = bf16(comb_e * gelu(t @ W1 + b1))
    gemm_kernel<1><<<dim3(32, 128), 256, 0, stream>>>(tbf, 768, w1t, 768, 768, 4096,
                                                      b1, comb, -1, nullptr, gall, nullptr, 4096);
    // GEMM3 (K=4096): out = gall @ [W2_0;..;W2_3] + sum_e comb_e*b2_e   (write-once)
    gemm_kernel<2><<<dim3(6, 128), 256, 0, stream>>>(gall, 4096, w2t2, 4096, 4096, 768,
                                                     nullptr, comb, 0, b2, nullptr, out, 768);
  } else {
    for (int e = 0; e < NEXP; e++) {
      gemm_kernel<1><<<dim3(8, 128), 256, 0, stream>>>(tbf, 768, w1t + (size_t)e * DFF_ * DIM, 768,
                                                       768, 1024, b1 + e * DFF_, comb, e, nullptr,
                                                       gbuf, nullptr, 1024);
      if (e == 0)
        gemm_kernel<2><<<dim3(6, 128), 256, 0, stream>>>(gbuf, 1024, w2t2 + (size_t)e * 1024, 4096,
                                                         1024, 768, nullptr, comb, 0, b2, nullptr,
                                                         out, 768);
      else
        gemm_kernel<3><<<dim3(6, 128), 256, 0, stream>>>(gbuf, 1024, w2t2 + (size_t)e * 1024, 4096,
                                                         1024, 768, nullptr, nullptr, 0, nullptr,
                                                         nullptr, out, 768);
    }
  }
}

// Round 4
// 572.799 us; speedup vs baseline: 1.2136x; 1.0656x over previous
//
#include <hip/hip_runtime.h>

#define DIM 768
#define NEXP 4
#define DFF_ 1024
#define CAP 16384  // per-expert slot capacity (max possible = T)

typedef __attribute__((ext_vector_type(4))) float f32x4;
typedef __attribute__((ext_vector_type(8))) short s16x8;

__device__ __forceinline__ unsigned short f32_to_bf16(float f) {
  unsigned int u = __float_as_uint(f);
  unsigned int r = (u + 0x7FFFu + ((u >> 16) & 1u)) >> 16;  // RNE
  return (unsigned short)r;
}

// ---------- transpose fp32 [R,C] -> bf16, generalized output addressing ----------
__global__ void transpose_bf16_kernel(const float* __restrict__ in,
                                      unsigned short* __restrict__ out,
                                      int R, int C, int ldo, int zOut) {
  __shared__ float tile[32][33];
  const int bx = blockIdx.x, by = blockIdx.y, bz = blockIdx.z;
  in  += (size_t)bz * R * C;
  out += (size_t)bz * zOut;
  const int tx = threadIdx.x, ty = threadIdx.y;
#pragma unroll
  for (int i = 0; i < 4; i++) {
    int r = by * 32 + ty + i * 8;
    int c = bx * 32 + tx;
    tile[ty + i * 8][tx] = in[(size_t)r * C + c];
  }
  __syncthreads();
#pragma unroll
  for (int i = 0; i < 4; i++) {
    int oc = bx * 32 + ty + i * 8;
    int orow = by * 32 + tx;
    out[(size_t)oc * ldo + orow] = f32_to_bf16(tile[tx][ty + i * 8]);
  }
}

// ---------- fp32 -> bf16 straight copy ----------
__global__ void convert_bf16_kernel(const float* __restrict__ in,
                                    unsigned short* __restrict__ out) {
  size_t i = ((size_t)blockIdx.x * 256 + threadIdx.x) * 8;
  float4 a = *(const float4*)(in + i);
  float4 b = *(const float4*)(in + i + 4);
  union { unsigned short u[8]; uint4 v; } pk;
  pk.u[0] = f32_to_bf16(a.x); pk.u[1] = f32_to_bf16(a.y);
  pk.u[2] = f32_to_bf16(a.z); pk.u[3] = f32_to_bf16(a.w);
  pk.u[4] = f32_to_bf16(b.x); pk.u[5] = f32_to_bf16(b.y);
  pk.u[6] = f32_to_bf16(b.z); pk.u[7] = f32_to_bf16(b.w);
  *(uint4*)(out + i) = pk.v;
}

// ---------- Wfg = W @ Wg, bgp = b @ Wg + bg (fp32 router weights) ----------
__global__ void wfg_kernel(const float* __restrict__ W, const float* __restrict__ Wg,
                           const float* __restrict__ b, const float* __restrict__ bg,
                           float* __restrict__ wfg, float* __restrict__ bgp) {
  int gid = blockIdx.x * 256 + threadIdx.x;
  if (gid < DIM * NEXP) {
    int k = gid >> 2, e = gid & 3;
    const float* wr = W + (size_t)k * DIM;
    float acc = 0.f;
    for (int d = 0; d < DIM; d++) acc += wr[d] * Wg[d * NEXP + e];
    wfg[gid] = acc;
  } else if (gid < DIM * NEXP + NEXP) {
    int e = gid - DIM * NEXP;
    float acc = bg[e];
    for (int d = 0; d < DIM; d++) acc += b[d] * Wg[d * NEXP + e];
    bgp[e] = acc;
  }
}

// ---------- router: fp32 logits, softmax, top2; writes (e1,e2),(g1,g2) ----------
// Also writes out[t,:] = sum_e comb_e * b2[e,:]  (base for GEMM3's atomic adds)
__global__ void router_kernel(const float* __restrict__ x, const float* __restrict__ wfg,
                              const float* __restrict__ bgp, const float* __restrict__ b2,
                              int2* __restrict__ rte, float2* __restrict__ rtg,
                              float* __restrict__ out) {
  __shared__ float wfgS[DIM * NEXP];
  __shared__ float b2S[NEXP * DIM];
  const int tid = threadIdx.x;
  for (int i = tid; i < DIM * NEXP; i += 256) { wfgS[i] = wfg[i]; b2S[i] = b2[i]; }
  __syncthreads();
  const int w = tid >> 6, lane = tid & 63;
  const size_t t = (size_t)blockIdx.x * 4 + w;
  const float* xr = x + t * DIM;
  float a0 = 0.f, a1 = 0.f, a2 = 0.f, a3 = 0.f;
#pragma unroll
  for (int i = 0; i < 12; i++) {
    int k = i * 64 + lane;
    float xv = xr[k];
    a0 += xv * wfgS[k * 4 + 0];
    a1 += xv * wfgS[k * 4 + 1];
    a2 += xv * wfgS[k * 4 + 2];
    a3 += xv * wfgS[k * 4 + 3];
  }
#pragma unroll
  for (int off = 32; off > 0; off >>= 1) {
    a0 += __shfl_xor(a0, off);
    a1 += __shfl_xor(a1, off);
    a2 += __shfl_xor(a2, off);
    a3 += __shfl_xor(a3, off);
  }
  float l[NEXP] = {a0 + bgp[0], a1 + bgp[1], a2 + bgp[2], a3 + bgp[3]};
  float m = fmaxf(fmaxf(l[0], l[1]), fmaxf(l[2], l[3]));
  float p[NEXP]; float s = 0.f;
#pragma unroll
  for (int e = 0; e < NEXP; e++) { p[e] = expf(l[e] - m); s += p[e]; }
#pragma unroll
  for (int e = 0; e < NEXP; e++) p[e] /= s;
  int i1 = 0;
#pragma unroll
  for (int e = 1; e < NEXP; e++) if (p[e] > p[i1]) i1 = e;  // ties -> lowest idx
  int i2 = -1;
#pragma unroll
  for (int e = 0; e < NEXP; e++) { if (e == i1) continue; if (i2 < 0 || p[e] > p[i2]) i2 = e; }
  float denom = p[i1] + p[i2];
  float c1 = p[i1] / denom, c2 = p[i2] / denom;
  float c[NEXP] = {0.f, 0.f, 0.f, 0.f};
  c[i1] = c1; c[i2] = c2;
  if (lane == 0) { rte[t] = make_int2(i1, i2); rtg[t] = make_float2(c1, c2); }
#pragma unroll
  for (int i = 0; i < 12; i++) {
    int n = i * 64 + lane;
    out[t * DIM + n] = c[0] * b2S[n] + c[1] * b2S[DIM + n] + c[2] * b2S[2 * DIM + n] + c[3] * b2S[3 * DIM + n];
  }
}

// ---------- assign: per-expert slot lists (block-aggregated histogram) ----------
__global__ void assign_kernel(const int2* __restrict__ rte, const float2* __restrict__ rtg,
                              int* __restrict__ cnt, int* __restrict__ idx_tok,
                              float* __restrict__ gate_sel) {
  __shared__ int hist[NEXP];
  __shared__ int base[NEXP];
  const int tid = threadIdx.x;
  if (tid < NEXP) hist[tid] = 0;
  __syncthreads();
  const int t = blockIdx.x * 256 + tid;
  int2 e = rte[t];
  float2 g = rtg[t];
  int r1 = atomicAdd(&hist[e.x], 1);
  int r2 = atomicAdd(&hist[e.y], 1);
  __syncthreads();
  if (tid < NEXP) base[tid] = atomicAdd(&cnt[tid], hist[tid]);
  __syncthreads();
  int s1 = base[e.x] + r1, s2 = base[e.y] + r2;
  idx_tok[e.x * CAP + s1] = t;  gate_sel[e.x * CAP + s1] = g.x;
  idx_tok[e.y * CAP + s2] = t;  gate_sel[e.y * CAP + s2] = g.y;
}

// ---------- bf16 MFMA GEMM, XCD-locality swizzled ----------
// MODE 0: dense. outB = bf16(acc + bias[col])                      (GEMM1)
// MODE 1: row-gathered A (token slots). outB = bf16(gate*gelu(acc+bias)) -> g  (GEMM2)
// MODE 2: contiguous A (g slots), scatter: atomicAdd(out[tok], acc)           (GEMM3)
// For MODE 1/2 gridDim.y = 4*CAP/128; seg = bm>>7; blocks past cnts[seg] exit.
template <int MODE, int CH>
__launch_bounds__(256)
__global__ void gemm_kernel(const unsigned short* __restrict__ A, const int lda,
                            const unsigned short* __restrict__ Bt, const int ldb,
                            const int K, const int N,
                            const float* __restrict__ bias,
                            const int* __restrict__ idx_tok,
                            const float* __restrict__ gate_sel,
                            const int* __restrict__ cnts,
                            unsigned short* __restrict__ outB,
                            float* __restrict__ outF, const int ldo) {
  // XCD-aware swizzle: xcd = lin%8 owns a contiguous m-range; within it,
  // n sweeps inside CH-m-tile chunks so L2 holds A-chunk + B-segment.
  const int lin = blockIdx.y * gridDim.x + blockIdx.x;
  const int xcd = lin & 7, t8 = lin >> 3;
  const int perXcdM = gridDim.y >> 3;
  const int mi = t8 % CH;
  const int rest = t8 / CH;
  const int bn = rest % gridDim.x;
  const int mc = rest / gridDim.x;
  const int bm = xcd * perXcdM + mc * CH + mi;
  const int bm0 = bm * 128, bn0 = bn * 128;

  int seg = 0, bmLoc = bm0, cnt = 1 << 30, segBase = 0;
  if constexpr (MODE != 0) {
    seg = bm >> 7;               // CAP/128 = 128 m-tiles per expert segment
    bmLoc = (bm & 127) * 128;
    segBase = seg * CAP;
    cnt = cnts[seg];
    if (bmLoc >= cnt) return;    // uniform early exit (before any barrier)
    Bt += (size_t)seg * N * ldb;
    if constexpr (MODE == 1) bias += (size_t)seg * N;
  }

  __shared__ unsigned short As[128 * 32];
  __shared__ unsigned short Bs[128 * 32];
  __shared__ int idxS[128];
  __shared__ float gateS[128];

  const int tid = threadIdx.x;
  const int w = tid >> 6;
  const int lane = tid & 63;

  if constexpr (MODE != 0) {
    if (tid < 128) {
      int r = bmLoc + tid;
      int cl = (r < cnt) ? r : bmLoc;  // clamp to block's first (valid) row
      idxS[tid] = idx_tok[segBase + cl];
      if constexpr (MODE == 1) gateS[tid] = gate_sel[segBase + cl];  // FIX: null in MODE 2
    }
    __syncthreads();
  }

  // per-thread staging rows are constant across K
  const int r0 = tid >> 2, r1 = 64 + r0;
  const int gq = (tid & 3) ^ (r0 & 3);  // quad XOR swizzle (r1&3 == r0&3)
  const unsigned short *aP0, *aP1;
  if constexpr (MODE == 0) {
    aP0 = A + (size_t)(bm0 + r0) * lda + gq * 8;
    aP1 = A + (size_t)(bm0 + r1) * lda + gq * 8;
  } else if constexpr (MODE == 1) {
    aP0 = A + (size_t)idxS[r0] * lda + gq * 8;
    aP1 = A + (size_t)idxS[r1] * lda + gq * 8;
  } else {
    aP0 = A + (size_t)(segBase + bmLoc + r0) * lda + gq * 8;
    aP1 = A + (size_t)(segBase + bmLoc + r1) * lda + gq * 8;
  }
  const unsigned short* bP0 = Bt + (size_t)(bn0 + r0) * ldb + gq * 8;
  const unsigned short* bP1 = Bt + (size_t)(bn0 + r1) * ldb + gq * 8;

  f32x4 acc[4][4];
#pragma unroll
  for (int i = 0; i < 4; i++)
#pragma unroll
    for (int j = 0; j < 4; j++) acc[i][j] = (f32x4){0.f, 0.f, 0.f, 0.f};

  const int quad = lane >> 4;
  const int m16 = lane & 15;
  const int wm = (w & 1) * 64;
  const int wn = (w >> 1) * 64;

  for (int k0 = 0; k0 < K; k0 += 32) {
    char* la0 = (char*)As + w * 1024;
    char* la1 = (char*)As + 4096 + w * 1024;
    char* lb0 = (char*)Bs + w * 1024;
    char* lb1 = (char*)Bs + 4096 + w * 1024;
    __builtin_amdgcn_global_load_lds((const __attribute__((address_space(1))) void*)(aP0 + k0),
                                     (__attribute__((address_space(3))) void*)la0, 16, 0, 0);
    __builtin_amdgcn_global_load_lds((const __attribute__((address_space(1))) void*)(aP1 + k0),
                                     (__attribute__((address_space(3))) void*)la1, 16, 0, 0);
    __builtin_amdgcn_global_load_lds((const __attribute__((address_space(1))) void*)(bP0 + k0),
                                     (__attribute__((address_space(3))) void*)lb0, 16, 0, 0);
    __builtin_amdgcn_global_load_lds((const __attribute__((address_space(1))) void*)(bP1 + k0),
                                     (__attribute__((address_space(3))) void*)lb1, 16, 0, 0);
    __syncthreads();
    const int sw = (quad ^ (m16 & 3)) * 16;  // de-swizzle
    s16x8 af[4], bf[4];
#pragma unroll
    for (int i = 0; i < 4; i++)
      af[i] = *(const s16x8*)((const char*)As + (wm + i * 16 + m16) * 64 + sw);
#pragma unroll
    for (int j = 0; j < 4; j++)
      bf[j] = *(const s16x8*)((const char*)Bs + (wn + j * 16 + m16) * 64 + sw);
#pragma unroll
    for (int i = 0; i < 4; i++)
#pragma unroll
      for (int j = 0; j < 4; j++)
        acc[i][j] = __builtin_amdgcn_mfma_f32_16x16x32_bf16(af[i], bf[j], acc[i][j], 0, 0, 0);
    __syncthreads();
  }

#pragma unroll
  for (int i = 0; i < 4; i++) {
    const int rloc = wm + i * 16 + quad * 4;
#pragma unroll
    for (int j = 0; j < 4; j++) {
      const int col = bn0 + wn + j * 16 + m16;
      if constexpr (MODE == 0) {
        float bv = bias[col];
#pragma unroll
        for (int r = 0; r < 4; r++)
          outB[(size_t)(bm0 + rloc + r) * ldo + col] = f32_to_bf16(acc[i][j][r] + bv);
      } else if constexpr (MODE == 1) {
        float bv = bias[col];
#pragma unroll
        for (int r = 0; r < 4; r++) {
          if (bmLoc + rloc + r < cnt) {
            float v = acc[i][j][r] + bv;
            float t3 = v + 0.044715f * v * v * v;
            float e2 = exp2f(t3 * 2.302208206984525f);  // e^{2u}, u=sqrt(2/pi)(v+0.044715v^3)
            float rc = __builtin_amdgcn_rcpf(1.0f + e2);
            float g = v - v * rc;
            outB[(size_t)(segBase + bmLoc + rloc + r) * ldo + col] =
                f32_to_bf16(g * gateS[rloc + r]);
          }
        }
      } else {
#pragma unroll
        for (int r = 0; r < 4; r++) {
          if (bmLoc + rloc + r < cnt) {
            int tok = idxS[rloc + r];
            atomicAdd(outF + (size_t)tok * ldo + col, acc[i][j][r]);
          }
        }
      }
    }
  }
}

extern "C" void kernel_launch(void* const* d_in, const int* in_sizes, int n_in,
                              void* d_out, int out_size, void* d_ws, size_t ws_size,
                              hipStream_t stream) {
  (void)in_sizes; (void)n_in; (void)out_size; (void)ws_size;
  const float* x  = (const float*)d_in[0];
  const float* W  = (const float*)d_in[1];
  const float* b  = (const float*)d_in[2];
  const float* Wg = (const float*)d_in[3];
  const float* bg = (const float*)d_in[4];
  const float* W1 = (const float*)d_in[5];
  const float* b1 = (const float*)d_in[6];
  const float* W2 = (const float*)d_in[7];
  const float* b2 = (const float*)d_in[8];
  float* out = (float*)d_out;
  char* ws = (char*)d_ws;

  // workspace layout (bytes); xbf/wt alias the g region (dead before g is written)
  unsigned short* tbf  = (unsigned short*)(ws + 0);          // [16384][768] bf16
  unsigned short* w1t  = (unsigned short*)(ws + 25165824);   // [4][1024][768] bf16
  unsigned short* w2t  = (unsigned short*)(ws + 31457280);   // [4][768][1024] bf16
  float* wfg           = (float*)(ws + 37748736);            // [768][4]
  float* bgp           = (float*)(ws + 37761024);            // [4]
  int2*  rte           = (int2*)(ws + 37761280);             // [16384]
  float2* rtg          = (float2*)(ws + 37892352);           // [16384]
  int*   cnt           = (int*)(ws + 38023424);              // [4]
  int*   idx_tok       = (int*)(ws + 38023680);              // [4][CAP]
  float* gate_sel      = (float*)(ws + 38285824);            // [4][CAP]
  unsigned short* g    = (unsigned short*)(ws + 38547968);   // [4*CAP][1024] bf16
  unsigned short* xbf  = (unsigned short*)(ws + 38547968);   // alias: [16384][768]
  unsigned short* wt   = (unsigned short*)(ws + 63713792);   // alias: [768][768]

  hipMemsetAsync(cnt, 0, NEXP * sizeof(int), stream);
  transpose_bf16_kernel<<<dim3(24, 24, 1), dim3(32, 8), 0, stream>>>(W, wt, 768, 768, 768, 589824);
  transpose_bf16_kernel<<<dim3(32, 24, 4), dim3(32, 8), 0, stream>>>(W1, w1t, 768, 1024, 768, 786432);
  transpose_bf16_kernel<<<dim3(24, 32, 4), dim3(32, 8), 0, stream>>>(W2, w2t, 1024, 768, 1024, 786432);
  convert_bf16_kernel<<<6144, 256, 0, stream>>>(x, xbf);
  wfg_kernel<<<13, 256, 0, stream>>>(W, Wg, b, bg, wfg, bgp);
  router_kernel<<<4096, 256, 0, stream>>>(x, wfg, bgp, b2, rte, rtg, out);
  assign_kernel<<<64, 256, 0, stream>>>(rte, rtg, cnt, idx_tok, gate_sel);

  // GEMM1: t = bf16(x @ W + b)          [dense, 19.3 GF]
  gemm_kernel<0, 8><<<dim3(6, 128), 256, 0, stream>>>(
      xbf, 768, wt, 768, 768, 768, b, nullptr, nullptr, nullptr, tbf, nullptr, 768);
  // GEMM2: g[slot] = bf16(gate * gelu(t[tok] @ W1_e + b1_e))   [gathered, 51.5 GF]
  gemm_kernel<1, 8><<<dim3(8, 512), 256, 0, stream>>>(
      tbf, 768, w1t, 768, 768, 1024, b1, idx_tok, gate_sel, cnt, g, nullptr, 1024);
  // GEMM3: out[tok] += g[slot] @ W2_e   [scatter atomicAdd, 51.5 GF]
  gemm_kernel<2, 8><<<dim3(6, 512), 256, 0, stream>>>(
      g, 1024, w2t, 1024, 1024, 768, nullptr, idx_tok, nullptr, cnt, nullptr, out, 768);
}

// Round 5
// 462.520 us; speedup vs baseline: 1.5030x; 1.2384x over previous
//
#include <hip/hip_runtime.h>

#define DIM 768
#define NEXP 4
#define DFF_ 1024
#define CAP 16384  // per-expert slot capacity (max possible = T)

typedef __attribute__((ext_vector_type(4))) float f32x4;
typedef __attribute__((ext_vector_type(8))) short s16x8;

__device__ __forceinline__ unsigned short f32_to_bf16(float f) {
  unsigned int u = __float_as_uint(f);
  unsigned int r = (u + 0x7FFFu + ((u >> 16) & 1u)) >> 16;  // RNE
  return (unsigned short)r;
}

// ---------- transpose fp32 [R,C] -> bf16, generalized output addressing ----------
__global__ void transpose_bf16_kernel(const float* __restrict__ in,
                                      unsigned short* __restrict__ out,
                                      int R, int C, int ldo, int zOut) {
  __shared__ float tile[32][33];
  const int bx = blockIdx.x, by = blockIdx.y, bz = blockIdx.z;
  in  += (size_t)bz * R * C;
  out += (size_t)bz * zOut;
  const int tx = threadIdx.x, ty = threadIdx.y;
#pragma unroll
  for (int i = 0; i < 4; i++) {
    int r = by * 32 + ty + i * 8;
    int c = bx * 32 + tx;
    tile[ty + i * 8][tx] = in[(size_t)r * C + c];
  }
  __syncthreads();
#pragma unroll
  for (int i = 0; i < 4; i++) {
    int oc = bx * 32 + ty + i * 8;
    int orow = by * 32 + tx;
    out[(size_t)oc * ldo + orow] = f32_to_bf16(tile[tx][ty + i * 8]);
  }
}

// ---------- fp32 -> bf16 straight copy ----------
__global__ void convert_bf16_kernel(const float* __restrict__ in,
                                    unsigned short* __restrict__ out) {
  size_t i = ((size_t)blockIdx.x * 256 + threadIdx.x) * 8;
  float4 a = *(const float4*)(in + i);
  float4 b = *(const float4*)(in + i + 4);
  union { unsigned short u[8]; uint4 v; } pk;
  pk.u[0] = f32_to_bf16(a.x); pk.u[1] = f32_to_bf16(a.y);
  pk.u[2] = f32_to_bf16(a.z); pk.u[3] = f32_to_bf16(a.w);
  pk.u[4] = f32_to_bf16(b.x); pk.u[5] = f32_to_bf16(b.y);
  pk.u[6] = f32_to_bf16(b.z); pk.u[7] = f32_to_bf16(b.w);
  *(uint4*)(out + i) = pk.v;
}

// ---------- Wfg = W @ Wg, bgp = b @ Wg + bg (fp32 router weights) ----------
__global__ void wfg_kernel(const float* __restrict__ W, const float* __restrict__ Wg,
                           const float* __restrict__ b, const float* __restrict__ bg,
                           float* __restrict__ wfg, float* __restrict__ bgp) {
  int gid = blockIdx.x * 256 + threadIdx.x;
  if (gid < DIM * NEXP) {
    int k = gid >> 2, e = gid & 3;
    const float* wr = W + (size_t)k * DIM;
    float acc = 0.f;
    for (int d = 0; d < DIM; d++) acc += wr[d] * Wg[d * NEXP + e];
    wfg[gid] = acc;
  } else if (gid < DIM * NEXP + NEXP) {
    int e = gid - DIM * NEXP;
    float acc = bg[e];
    for (int d = 0; d < DIM; d++) acc += b[d] * Wg[d * NEXP + e];
    bgp[e] = acc;
  }
}

// ---------- router: fp32 logits, softmax, top2; writes (e1,e2),(g1,g2) ----------
// Also writes out[t,:] = sum_e comb_e * b2[e,:]  (base for GEMM3's atomic adds)
__global__ void router_kernel(const float* __restrict__ x, const float* __restrict__ wfg,
                              const float* __restrict__ bgp, const float* __restrict__ b2,
                              int2* __restrict__ rte, float2* __restrict__ rtg,
                              float* __restrict__ out) {
  __shared__ float wfgS[DIM * NEXP];
  __shared__ float b2S[NEXP * DIM];
  const int tid = threadIdx.x;
  for (int i = tid; i < DIM * NEXP; i += 256) { wfgS[i] = wfg[i]; b2S[i] = b2[i]; }
  __syncthreads();
  const int w = tid >> 6, lane = tid & 63;
  const size_t t = (size_t)blockIdx.x * 4 + w;
  const float* xr = x + t * DIM;
  float a0 = 0.f, a1 = 0.f, a2 = 0.f, a3 = 0.f;
#pragma unroll
  for (int i = 0; i < 12; i++) {
    int k = i * 64 + lane;
    float xv = xr[k];
    a0 += xv * wfgS[k * 4 + 0];
    a1 += xv * wfgS[k * 4 + 1];
    a2 += xv * wfgS[k * 4 + 2];
    a3 += xv * wfgS[k * 4 + 3];
  }
#pragma unroll
  for (int off = 32; off > 0; off >>= 1) {
    a0 += __shfl_xor(a0, off);
    a1 += __shfl_xor(a1, off);
    a2 += __shfl_xor(a2, off);
    a3 += __shfl_xor(a3, off);
  }
  float l[NEXP] = {a0 + bgp[0], a1 + bgp[1], a2 + bgp[2], a3 + bgp[3]};
  float m = fmaxf(fmaxf(l[0], l[1]), fmaxf(l[2], l[3]));
  float p[NEXP]; float s = 0.f;
#pragma unroll
  for (int e = 0; e < NEXP; e++) { p[e] = expf(l[e] - m); s += p[e]; }
#pragma unroll
  for (int e = 0; e < NEXP; e++) p[e] /= s;
  int i1 = 0;
#pragma unroll
  for (int e = 1; e < NEXP; e++) if (p[e] > p[i1]) i1 = e;  // ties -> lowest idx
  int i2 = -1;
#pragma unroll
  for (int e = 0; e < NEXP; e++) { if (e == i1) continue; if (i2 < 0 || p[e] > p[i2]) i2 = e; }
  float denom = p[i1] + p[i2];
  float c1 = p[i1] / denom, c2 = p[i2] / denom;
  float c[NEXP] = {0.f, 0.f, 0.f, 0.f};
  c[i1] = c1; c[i2] = c2;
  if (lane == 0) { rte[t] = make_int2(i1, i2); rtg[t] = make_float2(c1, c2); }
#pragma unroll
  for (int i = 0; i < 12; i++) {
    int n = i * 64 + lane;
    out[t * DIM + n] = c[0] * b2S[n] + c[1] * b2S[DIM + n] + c[2] * b2S[2 * DIM + n] + c[3] * b2S[3 * DIM + n];
  }
}

// ---------- assign: per-expert slot lists (block-aggregated histogram) ----------
__global__ void assign_kernel(const int2* __restrict__ rte, const float2* __restrict__ rtg,
                              int* __restrict__ cnt, int* __restrict__ idx_tok,
                              float* __restrict__ gate_sel) {
  __shared__ int hist[NEXP];
  __shared__ int base[NEXP];
  const int tid = threadIdx.x;
  if (tid < NEXP) hist[tid] = 0;
  __syncthreads();
  const int t = blockIdx.x * 256 + tid;
  int2 e = rte[t];
  float2 g = rtg[t];
  int r1 = atomicAdd(&hist[e.x], 1);
  int r2 = atomicAdd(&hist[e.y], 1);
  __syncthreads();
  if (tid < NEXP) base[tid] = atomicAdd(&cnt[tid], hist[tid]);
  __syncthreads();
  int s1 = base[e.x] + r1, s2 = base[e.y] + r2;
  idx_tok[e.x * CAP + s1] = t;  gate_sel[e.x * CAP + s1] = g.x;
  idx_tok[e.y * CAP + s2] = t;  gate_sel[e.y * CAP + s2] = g.y;
}

// ---------- bf16 MFMA GEMM ----------
// MODE 0: dense. outB = bf16(acc + bias[col])                      (GEMM1)
// MODE 1: row-gathered A (token slots). outB = bf16(gate*gelu(acc+bias)) -> g  (GEMM2)
// MODE 2: contiguous A (g slots), scatter: atomicAdd(out[tok], acc)           (GEMM3)
// MODE 0: static XCD swizzle with CH-chunked n-sweep.
// MODE 1/2: COMPACTED active-tile domain -> XCD swizzle, so every XCD gets an
// equal share of real work regardless of routing balance (R4 bug: contiguous
// m-ranges put all active tiles of each segment on one XCD; half the XCDs idled).
template <int MODE, int CH>
__launch_bounds__(256)
__global__ void gemm_kernel(const unsigned short* __restrict__ A, const int lda,
                            const unsigned short* __restrict__ Bt, const int ldb,
                            const int K, const int N,
                            const float* __restrict__ bias,
                            const int* __restrict__ idx_tok,
                            const float* __restrict__ gate_sel,
                            const int* __restrict__ cnts,
                            unsigned short* __restrict__ outB,
                            float* __restrict__ outF, const int ldo) {
  const int lin = blockIdx.y * gridDim.x + blockIdx.x;
  const int nT = gridDim.x;
  const int xcd = lin & 7, t8 = lin >> 3;
  int bn = 0, bm0 = 0;
  int seg = 0, bmLoc = 0, cnt = 1 << 30, segBase = 0;

  if constexpr (MODE == 0) {
    const int perXcd = gridDim.y >> 3;
    const int mi = t8 % CH;
    const int rest = t8 / CH;
    bn = rest % nT;
    const int mc = rest / nT;
    bm0 = (xcd * perXcd + mc * CH + mi) * 128;
  } else {
    const int c0 = cnts[0], c1 = cnts[1], c2 = cnts[2], c3 = cnts[3];
    const int t0 = (c0 + 127) >> 7, t1 = (c1 + 127) >> 7,
              t2 = (c2 + 127) >> 7, t3 = (c3 + 127) >> 7;
    const int p1 = t0, p2 = p1 + t1, p3 = p2 + t2, tot = p3 + t3;
    const int perXcd = (tot + 7) >> 3;  // equal share of ACTIVE tiles per XCD
    bn = t8 % nT;
    const int mloc = t8 / nT;           // n fastest within XCD -> A-tile L2 reuse
    if (mloc >= perXcd) return;
    const int mIdx = xcd * perXcd + mloc;
    if (mIdx >= tot) return;
    seg = (mIdx >= p2) ? ((mIdx >= p3) ? 3 : 2) : ((mIdx >= p1) ? 1 : 0);
    const int pre = (seg == 3) ? p3 : (seg == 2) ? p2 : (seg == 1) ? p1 : 0;
    bmLoc = (mIdx - pre) * 128;
    segBase = seg * CAP;
    cnt = (seg == 3) ? c3 : (seg == 2) ? c2 : (seg == 1) ? c1 : c0;
    Bt += (size_t)seg * N * ldb;
    if constexpr (MODE == 1) bias += (size_t)seg * N;
  }

  __shared__ unsigned short As[128 * 32];
  __shared__ unsigned short Bs[128 * 32];
  __shared__ int idxS[128];
  __shared__ float gateS[128];

  const int tid = threadIdx.x;
  const int w = tid >> 6;
  const int lane = tid & 63;

  if constexpr (MODE != 0) {
    if (tid < 128) {
      int r = bmLoc + tid;
      int cl = (r < cnt) ? r : bmLoc;  // clamp to block's first (valid) row
      idxS[tid] = idx_tok[segBase + cl];
      if constexpr (MODE == 1) gateS[tid] = gate_sel[segBase + cl];
    }
    __syncthreads();
  }

  // per-thread staging rows are constant across K
  const int r0 = tid >> 2, r1 = 64 + r0;
  const int gq = (tid & 3) ^ (r0 & 3);  // quad XOR swizzle (r1&3 == r0&3)
  const unsigned short *aP0, *aP1;
  if constexpr (MODE == 0) {
    aP0 = A + (size_t)(bm0 + r0) * lda + gq * 8;
    aP1 = A + (size_t)(bm0 + r1) * lda + gq * 8;
  } else if constexpr (MODE == 1) {
    aP0 = A + (size_t)idxS[r0] * lda + gq * 8;
    aP1 = A + (size_t)idxS[r1] * lda + gq * 8;
  } else {
    aP0 = A + (size_t)(segBase + bmLoc + r0) * lda + gq * 8;
    aP1 = A + (size_t)(segBase + bmLoc + r1) * lda + gq * 8;
  }
  const unsigned short* bP0 = Bt + (size_t)(bn * 128 + r0) * ldb + gq * 8;
  const unsigned short* bP1 = Bt + (size_t)(bn * 128 + r1) * ldb + gq * 8;

  f32x4 acc[4][4];
#pragma unroll
  for (int i = 0; i < 4; i++)
#pragma unroll
    for (int j = 0; j < 4; j++) acc[i][j] = (f32x4){0.f, 0.f, 0.f, 0.f};

  const int quad = lane >> 4;
  const int m16 = lane & 15;
  const int wm = (w & 1) * 64;
  const int wn = (w >> 1) * 64;

  for (int k0 = 0; k0 < K; k0 += 32) {
    char* la0 = (char*)As + w * 1024;
    char* la1 = (char*)As + 4096 + w * 1024;
    char* lb0 = (char*)Bs + w * 1024;
    char* lb1 = (char*)Bs + 4096 + w * 1024;
    __builtin_amdgcn_global_load_lds((const __attribute__((address_space(1))) void*)(aP0 + k0),
                                     (__attribute__((address_space(3))) void*)la0, 16, 0, 0);
    __builtin_amdgcn_global_load_lds((const __attribute__((address_space(1))) void*)(aP1 + k0),
                                     (__attribute__((address_space(3))) void*)la1, 16, 0, 0);
    __builtin_amdgcn_global_load_lds((const __attribute__((address_space(1))) void*)(bP0 + k0),
                                     (__attribute__((address_space(3))) void*)lb0, 16, 0, 0);
    __builtin_amdgcn_global_load_lds((const __attribute__((address_space(1))) void*)(bP1 + k0),
                                     (__attribute__((address_space(3))) void*)lb1, 16, 0, 0);
    __syncthreads();
    const int sw = (quad ^ (m16 & 3)) * 16;  // de-swizzle
    s16x8 af[4], bf[4];
#pragma unroll
    for (int i = 0; i < 4; i++)
      af[i] = *(const s16x8*)((const char*)As + (wm + i * 16 + m16) * 64 + sw);
#pragma unroll
    for (int j = 0; j < 4; j++)
      bf[j] = *(const s16x8*)((const char*)Bs + (wn + j * 16 + m16) * 64 + sw);
#pragma unroll
    for (int i = 0; i < 4; i++)
#pragma unroll
      for (int j = 0; j < 4; j++)
        acc[i][j] = __builtin_amdgcn_mfma_f32_16x16x32_bf16(af[i], bf[j], acc[i][j], 0, 0, 0);
    __syncthreads();
  }

#pragma unroll
  for (int i = 0; i < 4; i++) {
    const int rloc = wm + i * 16 + quad * 4;
#pragma unroll
    for (int j = 0; j < 4; j++) {
      const int col = bn * 128 + wn + j * 16 + m16;
      if constexpr (MODE == 0) {
        float bv = bias[col];
#pragma unroll
        for (int r = 0; r < 4; r++)
          outB[(size_t)(bm0 + rloc + r) * ldo + col] = f32_to_bf16(acc[i][j][r] + bv);
      } else if constexpr (MODE == 1) {
        float bv = bias[col];
#pragma unroll
        for (int r = 0; r < 4; r++) {
          if (bmLoc + rloc + r < cnt) {
            float v = acc[i][j][r] + bv;
            float t3 = v + 0.044715f * v * v * v;
            float e2 = exp2f(t3 * 2.302208206984525f);  // e^{2u}, u=sqrt(2/pi)(v+0.044715v^3)
            float rc = __builtin_amdgcn_rcpf(1.0f + e2);
            float g = v - v * rc;
            outB[(size_t)(segBase + bmLoc + rloc + r) * ldo + col] =
                f32_to_bf16(g * gateS[rloc + r]);
          }
        }
      } else {
#pragma unroll
        for (int r = 0; r < 4; r++) {
          if (bmLoc + rloc + r < cnt) {
            int tok = idxS[rloc + r];
            atomicAdd(outF + (size_t)tok * ldo + col, acc[i][j][r]);
          }
        }
      }
    }
  }
}

extern "C" void kernel_launch(void* const* d_in, const int* in_sizes, int n_in,
                              void* d_out, int out_size, void* d_ws, size_t ws_size,
                              hipStream_t stream) {
  (void)in_sizes; (void)n_in; (void)out_size; (void)ws_size;
  const float* x  = (const float*)d_in[0];
  const float* W  = (const float*)d_in[1];
  const float* b  = (const float*)d_in[2];
  const float* Wg = (const float*)d_in[3];
  const float* bg = (const float*)d_in[4];
  const float* W1 = (const float*)d_in[5];
  const float* b1 = (const float*)d_in[6];
  const float* W2 = (const float*)d_in[7];
  const float* b2 = (const float*)d_in[8];
  float* out = (float*)d_out;
  char* ws = (char*)d_ws;

  // workspace layout (bytes); xbf/wt alias the g region (dead before g is written)
  unsigned short* tbf  = (unsigned short*)(ws + 0);          // [16384][768] bf16
  unsigned short* w1t  = (unsigned short*)(ws + 25165824);   // [4][1024][768] bf16
  unsigned short* w2t  = (unsigned short*)(ws + 31457280);   // [4][768][1024] bf16
  float* wfg           = (float*)(ws + 37748736);            // [768][4]
  float* bgp           = (float*)(ws + 37761024);            // [4]
  int2*  rte           = (int2*)(ws + 37761280);             // [16384]
  float2* rtg          = (float2*)(ws + 37892352);           // [16384]
  int*   cnt           = (int*)(ws + 38023424);              // [4]
  int*   idx_tok       = (int*)(ws + 38023680);              // [4][CAP]
  float* gate_sel      = (float*)(ws + 38285824);            // [4][CAP]
  unsigned short* g    = (unsigned short*)(ws + 38547968);   // [4*CAP][1024] bf16
  unsigned short* xbf  = (unsigned short*)(ws + 38547968);   // alias: [16384][768]
  unsigned short* wt   = (unsigned short*)(ws + 63713792);   // alias: [768][768]

  hipMemsetAsync(cnt, 0, NEXP * sizeof(int), stream);
  transpose_bf16_kernel<<<dim3(24, 24, 1), dim3(32, 8), 0, stream>>>(W, wt, 768, 768, 768, 589824);
  transpose_bf16_kernel<<<dim3(32, 24, 4), dim3(32, 8), 0, stream>>>(W1, w1t, 768, 1024, 768, 786432);
  transpose_bf16_kernel<<<dim3(24, 32, 4), dim3(32, 8), 0, stream>>>(W2, w2t, 1024, 768, 1024, 786432);
  convert_bf16_kernel<<<6144, 256, 0, stream>>>(x, xbf);
  wfg_kernel<<<13, 256, 0, stream>>>(W, Wg, b, bg, wfg, bgp);
  router_kernel<<<4096, 256, 0, stream>>>(x, wfg, bgp, b2, rte, rtg, out);
  assign_kernel<<<64, 256, 0, stream>>>(rte, rtg, cnt, idx_tok, gate_sel);

  // GEMM1: t = bf16(x @ W + b)          [dense, 19.3 GF]
  gemm_kernel<0, 8><<<dim3(6, 128), 256, 0, stream>>>(
      xbf, 768, wt, 768, 768, 768, b, nullptr, nullptr, nullptr, tbf, nullptr, 768);
  // GEMM2: g[slot] = bf16(gate * gelu(t[tok] @ W1_e + b1_e))   [gathered, 51.5 GF]
  // grid y=264: per-XCD capacity 264 blocks = ceil(259/8)=33 m-tiles x 8 n-tiles
  gemm_kernel<1, 8><<<dim3(8, 264), 256, 0, stream>>>(
      tbf, 768, w1t, 768, 768, 1024, b1, idx_tok, gate_sel, cnt, g, nullptr, 1024);
  // GEMM3: out[tok] += g[slot] @ W2_e   [scatter atomicAdd, 51.5 GF]
  gemm_kernel<2, 8><<<dim3(6, 264), 256, 0, stream>>>(
      g, 1024, w2t, 1024, 1024, 768, nullptr, idx_tok, nullptr, cnt, nullptr, out, 768);
}

// Round 6
// 429.757 us; speedup vs baseline: 1.6176x; 1.0762x over previous
//
#include <hip/hip_runtime.h>

#define DIM 768
#define NEXP 4
#define DFF_ 1024
#define CAP 16384  // per-expert slot capacity (max possible = T)

typedef __attribute__((ext_vector_type(4))) float f32x4;
typedef __attribute__((ext_vector_type(8))) short s16x8;

__device__ __forceinline__ unsigned short f32_to_bf16(float f) {
  unsigned int u = __float_as_uint(f);
  unsigned int r = (u + 0x7FFFu + ((u >> 16) & 1u)) >> 16;  // RNE
  return (unsigned short)r;
}
__device__ __forceinline__ float bf16_to_f32(unsigned short u) {
  return __uint_as_float(((unsigned int)u) << 16);
}

// ---------- transpose fp32 [R,C] -> bf16, generalized output addressing ----------
__global__ void transpose_bf16_kernel(const float* __restrict__ in,
                                      unsigned short* __restrict__ out,
                                      int R, int C, int ldo, int zOut) {
  __shared__ float tile[32][33];
  const int bx = blockIdx.x, by = blockIdx.y, bz = blockIdx.z;
  in  += (size_t)bz * R * C;
  out += (size_t)bz * zOut;
  const int tx = threadIdx.x, ty = threadIdx.y;
#pragma unroll
  for (int i = 0; i < 4; i++) {
    int r = by * 32 + ty + i * 8;
    int c = bx * 32 + tx;
    tile[ty + i * 8][tx] = in[(size_t)r * C + c];
  }
  __syncthreads();
#pragma unroll
  for (int i = 0; i < 4; i++) {
    int oc = bx * 32 + ty + i * 8;
    int orow = by * 32 + tx;
    out[(size_t)oc * ldo + orow] = f32_to_bf16(tile[tx][ty + i * 8]);
  }
}

// ---------- fp32 -> bf16 straight copy ----------
__global__ void convert_bf16_kernel(const float* __restrict__ in,
                                    unsigned short* __restrict__ out) {
  size_t i = ((size_t)blockIdx.x * 256 + threadIdx.x) * 8;
  float4 a = *(const float4*)(in + i);
  float4 b = *(const float4*)(in + i + 4);
  union { unsigned short u[8]; uint4 v; } pk;
  pk.u[0] = f32_to_bf16(a.x); pk.u[1] = f32_to_bf16(a.y);
  pk.u[2] = f32_to_bf16(a.z); pk.u[3] = f32_to_bf16(a.w);
  pk.u[4] = f32_to_bf16(b.x); pk.u[5] = f32_to_bf16(b.y);
  pk.u[6] = f32_to_bf16(b.z); pk.u[7] = f32_to_bf16(b.w);
  *(uint4*)(out + i) = pk.v;
}

// ---------- Wfg = W @ Wg, bgp = b @ Wg + bg (fp32 router weights) ----------
__global__ void wfg_kernel(const float* __restrict__ W, const float* __restrict__ Wg,
                           const float* __restrict__ b, const float* __restrict__ bg,
                           float* __restrict__ wfg, float* __restrict__ bgp) {
  int gid = blockIdx.x * 256 + threadIdx.x;
  if (gid < DIM * NEXP) {
    int k = gid >> 2, e = gid & 3;
    const float* wr = W + (size_t)k * DIM;
    float acc = 0.f;
    for (int d = 0; d < DIM; d++) acc += wr[d] * Wg[d * NEXP + e];
    wfg[gid] = acc;
  } else if (gid < DIM * NEXP + NEXP) {
    int e = gid - DIM * NEXP;
    float acc = bg[e];
    for (int d = 0; d < DIM; d++) acc += b[d] * Wg[d * NEXP + e];
    bgp[e] = acc;
  }
}

// ---------- router: fp32 logits, softmax, top2; writes (e1,e2),(g1,g2) ----------
__global__ void router_kernel(const float* __restrict__ x, const float* __restrict__ wfg,
                              const float* __restrict__ bgp,
                              int2* __restrict__ rte, float2* __restrict__ rtg) {
  __shared__ float wfgS[DIM * NEXP];
  const int tid = threadIdx.x;
  for (int i = tid; i < DIM * NEXP; i += 256) wfgS[i] = wfg[i];
  __syncthreads();
  const int w = tid >> 6, lane = tid & 63;
  const size_t t = (size_t)blockIdx.x * 4 + w;
  const float* xr = x + t * DIM;
  float a0 = 0.f, a1 = 0.f, a2 = 0.f, a3 = 0.f;
#pragma unroll
  for (int i = 0; i < 12; i++) {
    int k = i * 64 + lane;
    float xv = xr[k];
    a0 += xv * wfgS[k * 4 + 0];
    a1 += xv * wfgS[k * 4 + 1];
    a2 += xv * wfgS[k * 4 + 2];
    a3 += xv * wfgS[k * 4 + 3];
  }
#pragma unroll
  for (int off = 32; off > 0; off >>= 1) {
    a0 += __shfl_xor(a0, off);
    a1 += __shfl_xor(a1, off);
    a2 += __shfl_xor(a2, off);
    a3 += __shfl_xor(a3, off);
  }
  if (lane == 0) {
    float l[NEXP] = {a0 + bgp[0], a1 + bgp[1], a2 + bgp[2], a3 + bgp[3]};
    float m = fmaxf(fmaxf(l[0], l[1]), fmaxf(l[2], l[3]));
    float p[NEXP]; float s = 0.f;
#pragma unroll
    for (int e = 0; e < NEXP; e++) { p[e] = expf(l[e] - m); s += p[e]; }
#pragma unroll
    for (int e = 0; e < NEXP; e++) p[e] /= s;
    int i1 = 0;
#pragma unroll
    for (int e = 1; e < NEXP; e++) if (p[e] > p[i1]) i1 = e;  // ties -> lowest idx
    int i2 = -1;
#pragma unroll
    for (int e = 0; e < NEXP; e++) { if (e == i1) continue; if (i2 < 0 || p[e] > p[i2]) i2 = e; }
    float denom = p[i1] + p[i2];
    rte[t] = make_int2(i1, i2);
    rtg[t] = make_float2(p[i1] / denom, p[i2] / denom);
  }
}

// ---------- assign: per-expert slot lists + token->slot map ----------
__global__ void assign_kernel(const int2* __restrict__ rte, const float2* __restrict__ rtg,
                              int* __restrict__ cnt, int* __restrict__ idx_tok,
                              float* __restrict__ gate_sel, int2* __restrict__ tok_slot) {
  __shared__ int hist[NEXP];
  __shared__ int base[NEXP];
  const int tid = threadIdx.x;
  if (tid < NEXP) hist[tid] = 0;
  __syncthreads();
  const int t = blockIdx.x * 256 + tid;
  int2 e = rte[t];
  float2 g = rtg[t];
  int r1 = atomicAdd(&hist[e.x], 1);
  int r2 = atomicAdd(&hist[e.y], 1);
  __syncthreads();
  if (tid < NEXP) base[tid] = atomicAdd(&cnt[tid], hist[tid]);
  __syncthreads();
  int s1 = base[e.x] + r1, s2 = base[e.y] + r2;
  idx_tok[e.x * CAP + s1] = t;  gate_sel[e.x * CAP + s1] = g.x;
  idx_tok[e.y * CAP + s2] = t;  gate_sel[e.y * CAP + s2] = g.y;
  tok_slot[t] = make_int2((e.x << 14) | s1, (e.y << 14) | s2);  // packed e|slot
}

// ---------- combine: out[t] = y[row1] + y[row2] + c1*b2[e1] + c2*b2[e2] ----------
__global__ void combine_kernel(const unsigned short* __restrict__ y,
                               const int2* __restrict__ tok_slot,
                               const float2* __restrict__ rtg,
                               const int* __restrict__ cnts,
                               const float* __restrict__ b2,
                               float* __restrict__ out) {
  __shared__ float b2S[NEXP * DIM];
  const int tid = threadIdx.x;
  for (int i = tid; i < NEXP * DIM; i += 256) b2S[i] = b2[i];
  // compacted-padded row bases (tiles of 128)
  const int t0 = (cnts[0] + 127) >> 7, t1 = (cnts[1] + 127) >> 7, t2 = (cnts[2] + 127) >> 7;
  const int rb[NEXP] = {0, t0 * 128, (t0 + t1) * 128, (t0 + t1 + t2) * 128};
  __syncthreads();
  const int w = tid >> 6, lane = tid & 63;
  const size_t t = (size_t)blockIdx.x * 4 + w;
  int2 v = tok_slot[t];
  float2 cg = rtg[t];
  const int e1 = v.x >> 14, s1 = v.x & (CAP - 1);
  const int e2 = v.y >> 14, s2 = v.y & (CAP - 1);
  const unsigned short* y1 = y + (size_t)(rb[e1] + s1) * DIM;
  const unsigned short* y2 = y + (size_t)(rb[e2] + s2) * DIM;
  float* op = out + t * DIM;
  const float* bp1 = b2S + e1 * DIM;
  const float* bp2 = b2S + e2 * DIM;
#pragma unroll
  for (int k = 0; k < 12; k++) {
    int n = k * 64 + lane;
    op[n] = bf16_to_f32(y1[n]) + bf16_to_f32(y2[n]) + cg.x * bp1[n] + cg.y * bp2[n];
  }
}

// ---------- bf16 MFMA GEMM ----------
// MODE 0: dense. outB = bf16(acc + bias[col])                                  (GEMM1)
// MODE 1: row-gathered A (token slots) -> g rows (compacted-padded), gelu*gate (GEMM2)
// MODE 2: contiguous A (g rows) -> y rows (compacted-padded), plain bf16 store (GEMM3)
// MODE 1/2: compacted active-tile domain -> XCD swizzle (equal real work/XCD).
template <int MODE, int CH>
__launch_bounds__(256)
__global__ void gemm_kernel(const unsigned short* __restrict__ A, const int lda,
                            const unsigned short* __restrict__ Bt, const int ldb,
                            const int K, const int N,
                            const float* __restrict__ bias,
                            const int* __restrict__ idx_tok,
                            const float* __restrict__ gate_sel,
                            const int* __restrict__ cnts,
                            unsigned short* __restrict__ outB, const int ldo) {
  const int lin = blockIdx.y * gridDim.x + blockIdx.x;
  const int nT = gridDim.x;
  const int xcd = lin & 7, t8 = lin >> 3;
  int bn = 0, bm0 = 0;
  int bmLoc = 0, cnt = 1 << 30, segBase = 0, gRow0 = 0;

  if constexpr (MODE == 0) {
    const int perXcd = gridDim.y >> 3;
    const int mi = t8 % CH;
    const int rest = t8 / CH;
    bn = rest % nT;
    const int mc = rest / nT;
    bm0 = (xcd * perXcd + mc * CH + mi) * 128;
  } else {
    const int c0 = cnts[0], c1 = cnts[1], c2 = cnts[2], c3 = cnts[3];
    const int t0 = (c0 + 127) >> 7, t1 = (c1 + 127) >> 7,
              t2 = (c2 + 127) >> 7, t3 = (c3 + 127) >> 7;
    const int p1 = t0, p2 = p1 + t1, p3 = p2 + t2, tot = p3 + t3;
    const int perXcd = (tot + 7) >> 3;  // equal share of ACTIVE tiles per XCD
    bn = t8 % nT;
    const int mloc = t8 / nT;           // n fastest within XCD -> A-tile L2 reuse
    if (mloc >= perXcd) return;
    const int mIdx = xcd * perXcd + mloc;
    if (mIdx >= tot) return;
    const int seg = (mIdx >= p2) ? ((mIdx >= p3) ? 3 : 2) : ((mIdx >= p1) ? 1 : 0);
    const int pre = (seg == 3) ? p3 : (seg == 2) ? p2 : (seg == 1) ? p1 : 0;
    bmLoc = (mIdx - pre) * 128;
    segBase = seg * CAP;
    gRow0 = mIdx * 128;                 // compacted-padded row base = tileIdx*128
    cnt = (seg == 3) ? c3 : (seg == 2) ? c2 : (seg == 1) ? c1 : c0;
    Bt += (size_t)seg * N * ldb;
    if constexpr (MODE == 1) bias += (size_t)seg * N;
  }

  __shared__ unsigned short As[128 * 32];
  __shared__ unsigned short Bs[128 * 32];
  __shared__ int idxS[128];
  __shared__ float gateS[128];

  const int tid = threadIdx.x;
  const int w = tid >> 6;
  const int lane = tid & 63;

  if constexpr (MODE == 1) {
    if (tid < 128) {
      int r = bmLoc + tid;
      int cl = (r < cnt) ? r : bmLoc;  // clamp to block's first (valid) row
      idxS[tid] = idx_tok[segBase + cl];
      gateS[tid] = gate_sel[segBase + cl];
    }
    __syncthreads();
  }

  // per-thread staging rows are constant across K
  const int r0 = tid >> 2, r1 = 64 + r0;
  const int gq = (tid & 3) ^ (r0 & 3);  // quad XOR swizzle (r1&3 == r0&3)
  const unsigned short *aP0, *aP1;
  if constexpr (MODE == 0) {
    aP0 = A + (size_t)(bm0 + r0) * lda + gq * 8;
    aP1 = A + (size_t)(bm0 + r1) * lda + gq * 8;
  } else if constexpr (MODE == 1) {
    aP0 = A + (size_t)idxS[r0] * lda + gq * 8;
    aP1 = A + (size_t)idxS[r1] * lda + gq * 8;
  } else {
    aP0 = A + (size_t)(gRow0 + r0) * lda + gq * 8;  // contiguous compacted rows
    aP1 = A + (size_t)(gRow0 + r1) * lda + gq * 8;
  }
  const unsigned short* bP0 = Bt + (size_t)(bn * 128 + r0) * ldb + gq * 8;
  const unsigned short* bP1 = Bt + (size_t)(bn * 128 + r1) * ldb + gq * 8;

  f32x4 acc[4][4];
#pragma unroll
  for (int i = 0; i < 4; i++)
#pragma unroll
    for (int j = 0; j < 4; j++) acc[i][j] = (f32x4){0.f, 0.f, 0.f, 0.f};

  const int quad = lane >> 4;
  const int m16 = lane & 15;
  const int wm = (w & 1) * 64;
  const int wn = (w >> 1) * 64;

  for (int k0 = 0; k0 < K; k0 += 32) {
    char* la0 = (char*)As + w * 1024;
    char* la1 = (char*)As + 4096 + w * 1024;
    char* lb0 = (char*)Bs + w * 1024;
    char* lb1 = (char*)Bs + 4096 + w * 1024;
    __builtin_amdgcn_global_load_lds((const __attribute__((address_space(1))) void*)(aP0 + k0),
                                     (__attribute__((address_space(3))) void*)la0, 16, 0, 0);
    __builtin_amdgcn_global_load_lds((const __attribute__((address_space(1))) void*)(aP1 + k0),
                                     (__attribute__((address_space(3))) void*)la1, 16, 0, 0);
    __builtin_amdgcn_global_load_lds((const __attribute__((address_space(1))) void*)(bP0 + k0),
                                     (__attribute__((address_space(3))) void*)lb0, 16, 0, 0);
    __builtin_amdgcn_global_load_lds((const __attribute__((address_space(1))) void*)(bP1 + k0),
                                     (__attribute__((address_space(3))) void*)lb1, 16, 0, 0);
    __syncthreads();
    const int sw = (quad ^ (m16 & 3)) * 16;  // de-swizzle
    s16x8 af[4], bf[4];
#pragma unroll
    for (int i = 0; i < 4; i++)
      af[i] = *(const s16x8*)((const char*)As + (wm + i * 16 + m16) * 64 + sw);
#pragma unroll
    for (int j = 0; j < 4; j++)
      bf[j] = *(const s16x8*)((const char*)Bs + (wn + j * 16 + m16) * 64 + sw);
#pragma unroll
    for (int i = 0; i < 4; i++)
#pragma unroll
      for (int j = 0; j < 4; j++)
        acc[i][j] = __builtin_amdgcn_mfma_f32_16x16x32_bf16(af[i], bf[j], acc[i][j], 0, 0, 0);
    __syncthreads();
  }

#pragma unroll
  for (int i = 0; i < 4; i++) {
    const int rloc = wm + i * 16 + quad * 4;
#pragma unroll
    for (int j = 0; j < 4; j++) {
      const int col = bn * 128 + wn + j * 16 + m16;
      if constexpr (MODE == 0) {
        float bv = bias[col];
#pragma unroll
        for (int r = 0; r < 4; r++)
          outB[(size_t)(bm0 + rloc + r) * ldo + col] = f32_to_bf16(acc[i][j][r] + bv);
      } else if constexpr (MODE == 1) {
        float bv = bias[col];
#pragma unroll
        for (int r = 0; r < 4; r++) {
          if (bmLoc + rloc + r < cnt) {
            float v = acc[i][j][r] + bv;
            float t3 = v + 0.044715f * v * v * v;
            float e2 = exp2f(t3 * 2.302208206984525f);  // e^{2u}, u=sqrt(2/pi)(v+0.044715v^3)
            float rc = __builtin_amdgcn_rcpf(1.0f + e2);
            float g = v - v * rc;
            outB[(size_t)(gRow0 + rloc + r) * ldo + col] = f32_to_bf16(g * gateS[rloc + r]);
          }
        }
      } else {
#pragma unroll
        for (int r = 0; r < 4; r++) {
          if (bmLoc + rloc + r < cnt)
            outB[(size_t)(gRow0 + rloc + r) * ldo + col] = f32_to_bf16(acc[i][j][r]);
        }
      }
    }
  }
}

extern "C" void kernel_launch(void* const* d_in, const int* in_sizes, int n_in,
                              void* d_out, int out_size, void* d_ws, size_t ws_size,
                              hipStream_t stream) {
  (void)in_sizes; (void)n_in; (void)out_size; (void)ws_size;
  const float* x  = (const float*)d_in[0];
  const float* W  = (const float*)d_in[1];
  const float* b  = (const float*)d_in[2];
  const float* Wg = (const float*)d_in[3];
  const float* bg = (const float*)d_in[4];
  const float* W1 = (const float*)d_in[5];
  const float* b1 = (const float*)d_in[6];
  const float* W2 = (const float*)d_in[7];
  const float* b2 = (const float*)d_in[8];
  float* out = (float*)d_out;
  char* ws = (char*)d_ws;

  // workspace layout (bytes); xbf/wt alias the g region (dead before g is written)
  unsigned short* tbf  = (unsigned short*)(ws + 0);          // [16384][768] bf16
  unsigned short* w1t  = (unsigned short*)(ws + 25165824);   // [4][1024][768] bf16
  unsigned short* w2t  = (unsigned short*)(ws + 31457280);   // [4][768][1024] bf16
  float* wfg           = (float*)(ws + 37748736);            // [768][4]
  float* bgp           = (float*)(ws + 37761024);            // [4]
  int2*  rte           = (int2*)(ws + 37761280);             // [16384]
  float2* rtg          = (float2*)(ws + 37892352);           // [16384]
  int*   cnt           = (int*)(ws + 38023424);              // [4]
  int*   idx_tok       = (int*)(ws + 38023680);              // [4][CAP]
  float* gate_sel      = (float*)(ws + 38285824);            // [4][CAP]
  int2*  tok_slot      = (int2*)(ws + 38547968);             // [16384]
  unsigned short* g    = (unsigned short*)(ws + 38679040);   // [<=33152][1024] bf16 (compacted)
  unsigned short* xbf  = (unsigned short*)(ws + 38679040);   // alias: [16384][768]
  unsigned short* wt   = (unsigned short*)(ws + 63844864);   // alias: [768][768]
  unsigned short* y    = (unsigned short*)(ws + 106574336);  // [<=33152][768] bf16 (compacted)
  // end: 157,495,808 < ~198 MB proven available (R2 merged path ran)

  hipMemsetAsync(cnt, 0, NEXP * sizeof(int), stream);
  transpose_bf16_kernel<<<dim3(24, 24, 1), dim3(32, 8), 0, stream>>>(W, wt, 768, 768, 768, 589824);
  transpose_bf16_kernel<<<dim3(32, 24, 4), dim3(32, 8), 0, stream>>>(W1, w1t, 768, 1024, 768, 786432);
  transpose_bf16_kernel<<<dim3(24, 32, 4), dim3(32, 8), 0, stream>>>(W2, w2t, 1024, 768, 1024, 786432);
  convert_bf16_kernel<<<6144, 256, 0, stream>>>(x, xbf);
  wfg_kernel<<<13, 256, 0, stream>>>(W, Wg, b, bg, wfg, bgp);
  router_kernel<<<4096, 256, 0, stream>>>(x, wfg, bgp, rte, rtg);
  assign_kernel<<<64, 256, 0, stream>>>(rte, rtg, cnt, idx_tok, gate_sel, tok_slot);

  // GEMM1: t = bf16(x @ W + b)          [dense, 19.3 GF]
  gemm_kernel<0, 8><<<dim3(6, 128), 256, 0, stream>>>(
      xbf, 768, wt, 768, 768, 768, b, nullptr, nullptr, nullptr, tbf, 768);
  // GEMM2: g[row] = bf16(gate * gelu(t[tok] @ W1_e + b1_e))   [gathered, 51.5 GF]
  gemm_kernel<1, 8><<<dim3(8, 264), 256, 0, stream>>>(
      tbf, 768, w1t, 768, 768, 1024, b1, idx_tok, gate_sel, cnt, g, 1024);
  // GEMM3: y[row] = bf16(g[row] @ W2_e)   [write-once, 51.5 GF]
  gemm_kernel<2, 8><<<dim3(6, 264), 256, 0, stream>>>(
      g, 1024, w2t, 1024, 1024, 768, nullptr, nullptr, nullptr, cnt, y, 768);
  // combine: out[t] = y[slot1] + y[slot2] + c1*b2[e1] + c2*b2[e2]
  combine_kernel<<<4096, 256, 0, stream>>>(y, tok_slot, rtg, cnt, b2, out);
}

// Round 7
// 422.303 us; speedup vs baseline: 1.6461x; 1.0177x over previous
//
#include <hip/hip_runtime.h>

#define DIM 768
#define NEXP 4
#define DFF_ 1024
#define CAP 16384  // per-expert slot capacity (max possible = T)

typedef __attribute__((ext_vector_type(4))) float f32x4;
typedef __attribute__((ext_vector_type(8))) short s16x8;

__device__ __forceinline__ unsigned short f32_to_bf16(float f) {
  unsigned int u = __float_as_uint(f);
  unsigned int r = (u + 0x7FFFu + ((u >> 16) & 1u)) >> 16;  // RNE
  return (unsigned short)r;
}
__device__ __forceinline__ float bf16_to_f32(unsigned short u) {
  return __uint_as_float(((unsigned int)u) << 16);
}

// ---------- transpose fp32 [R,C] -> bf16, generalized output addressing ----------
__global__ void transpose_bf16_kernel(const float* __restrict__ in,
                                      unsigned short* __restrict__ out,
                                      int R, int C, int ldo, int zOut) {
  __shared__ float tile[32][33];
  const int bx = blockIdx.x, by = blockIdx.y, bz = blockIdx.z;
  in  += (size_t)bz * R * C;
  out += (size_t)bz * zOut;
  const int tx = threadIdx.x, ty = threadIdx.y;
#pragma unroll
  for (int i = 0; i < 4; i++) {
    int r = by * 32 + ty + i * 8;
    int c = bx * 32 + tx;
    tile[ty + i * 8][tx] = in[(size_t)r * C + c];
  }
  __syncthreads();
#pragma unroll
  for (int i = 0; i < 4; i++) {
    int oc = bx * 32 + ty + i * 8;
    int orow = by * 32 + tx;
    out[(size_t)oc * ldo + orow] = f32_to_bf16(tile[tx][ty + i * 8]);
  }
}

// ---------- Wfg = W @ Wg, bgp = b @ Wg + bg (fp32 router weights) ----------
__global__ void wfg_kernel(const float* __restrict__ W, const float* __restrict__ Wg,
                           const float* __restrict__ b, const float* __restrict__ bg,
                           float* __restrict__ wfg, float* __restrict__ bgp) {
  int gid = blockIdx.x * 256 + threadIdx.x;
  if (gid < DIM * NEXP) {
    int k = gid >> 2, e = gid & 3;
    const float* wr = W + (size_t)k * DIM;
    float acc = 0.f;
    for (int d = 0; d < DIM; d++) acc += wr[d] * Wg[d * NEXP + e];
    wfg[gid] = acc;
  } else if (gid < DIM * NEXP + NEXP) {
    int e = gid - DIM * NEXP;
    float acc = bg[e];
    for (int d = 0; d < DIM; d++) acc += b[d] * Wg[d * NEXP + e];
    bgp[e] = acc;
  }
}

// ---------- router (+ fused x->bf16 convert): fp32 logits, softmax, top2 ----------
__global__ void router_kernel(const float* __restrict__ x, const float* __restrict__ wfg,
                              const float* __restrict__ bgp,
                              int2* __restrict__ rte, float2* __restrict__ rtg,
                              unsigned short* __restrict__ xbf) {
  __shared__ float wfgS[DIM * NEXP];
  const int tid = threadIdx.x;
  for (int i = tid; i < DIM * NEXP; i += 256) wfgS[i] = wfg[i];
  __syncthreads();
  const int w = tid >> 6, lane = tid & 63;
  const size_t t = (size_t)blockIdx.x * 4 + w;
  const float* xr = x + t * DIM;
  unsigned short* xbr = xbf + t * DIM;
  float a0 = 0.f, a1 = 0.f, a2 = 0.f, a3 = 0.f;
#pragma unroll
  for (int i = 0; i < 6; i++) {
    int k = i * 128 + lane * 2;
    float2 xv = *(const float2*)(xr + k);
    ushort2 pk;
    pk.x = f32_to_bf16(xv.x);
    pk.y = f32_to_bf16(xv.y);
    *(ushort2*)(xbr + k) = pk;  // fused convert (saves a 50 MB re-read dispatch)
    a0 += xv.x * wfgS[k * 4 + 0] + xv.y * wfgS[k * 4 + 4];
    a1 += xv.x * wfgS[k * 4 + 1] + xv.y * wfgS[k * 4 + 5];
    a2 += xv.x * wfgS[k * 4 + 2] + xv.y * wfgS[k * 4 + 6];
    a3 += xv.x * wfgS[k * 4 + 3] + xv.y * wfgS[k * 4 + 7];
  }
#pragma unroll
  for (int off = 32; off > 0; off >>= 1) {
    a0 += __shfl_xor(a0, off);
    a1 += __shfl_xor(a1, off);
    a2 += __shfl_xor(a2, off);
    a3 += __shfl_xor(a3, off);
  }
  if (lane == 0) {
    float l[NEXP] = {a0 + bgp[0], a1 + bgp[1], a2 + bgp[2], a3 + bgp[3]};
    float m = fmaxf(fmaxf(l[0], l[1]), fmaxf(l[2], l[3]));
    float p[NEXP]; float s = 0.f;
#pragma unroll
    for (int e = 0; e < NEXP; e++) { p[e] = expf(l[e] - m); s += p[e]; }
#pragma unroll
    for (int e = 0; e < NEXP; e++) p[e] /= s;
    int i1 = 0;
#pragma unroll
    for (int e = 1; e < NEXP; e++) if (p[e] > p[i1]) i1 = e;  // ties -> lowest idx
    int i2 = -1;
#pragma unroll
    for (int e = 0; e < NEXP; e++) { if (e == i1) continue; if (i2 < 0 || p[e] > p[i2]) i2 = e; }
    float denom = p[i1] + p[i2];
    rte[t] = make_int2(i1, i2);
    rtg[t] = make_float2(p[i1] / denom, p[i2] / denom);
  }
}

// ---------- assign: per-expert slot lists + token->slot map ----------
__global__ void assign_kernel(const int2* __restrict__ rte, const float2* __restrict__ rtg,
                              int* __restrict__ cnt, int* __restrict__ idx_tok,
                              float* __restrict__ gate_sel, int2* __restrict__ tok_slot) {
  __shared__ int hist[NEXP];
  __shared__ int base[NEXP];
  const int tid = threadIdx.x;
  if (tid < NEXP) hist[tid] = 0;
  __syncthreads();
  const int t = blockIdx.x * 256 + tid;
  int2 e = rte[t];
  float2 g = rtg[t];
  int r1 = atomicAdd(&hist[e.x], 1);
  int r2 = atomicAdd(&hist[e.y], 1);
  __syncthreads();
  if (tid < NEXP) base[tid] = atomicAdd(&cnt[tid], hist[tid]);
  __syncthreads();
  int s1 = base[e.x] + r1, s2 = base[e.y] + r2;
  idx_tok[e.x * CAP + s1] = t;  gate_sel[e.x * CAP + s1] = g.x;
  idx_tok[e.y * CAP + s2] = t;  gate_sel[e.y * CAP + s2] = g.y;
  tok_slot[t] = make_int2((e.x << 14) | s1, (e.y << 14) | s2);  // packed e|slot
}

// ---------- combine: out[t] = y[row1] + y[row2] + c1*b2[e1] + c2*b2[e2] ----------
__global__ void combine_kernel(const unsigned short* __restrict__ y,
                               const int2* __restrict__ tok_slot,
                               const float2* __restrict__ rtg,
                               const int* __restrict__ cnts,
                               const float* __restrict__ b2,
                               float* __restrict__ out) {
  __shared__ float b2S[NEXP * DIM];
  const int tid = threadIdx.x;
  for (int i = tid; i < NEXP * DIM; i += 256) b2S[i] = b2[i];
  const int t0 = (cnts[0] + 127) >> 7, t1 = (cnts[1] + 127) >> 7, t2 = (cnts[2] + 127) >> 7;
  const int rb[NEXP] = {0, t0 * 128, (t0 + t1) * 128, (t0 + t1 + t2) * 128};
  __syncthreads();
  const int w = tid >> 6, lane = tid & 63;
  const size_t t = (size_t)blockIdx.x * 4 + w;
  int2 v = tok_slot[t];
  float2 cg = rtg[t];
  const int e1 = v.x >> 14, s1 = v.x & (CAP - 1);
  const int e2 = v.y >> 14, s2 = v.y & (CAP - 1);
  const unsigned short* y1 = y + (size_t)(rb[e1] + s1) * DIM;
  const unsigned short* y2 = y + (size_t)(rb[e2] + s2) * DIM;
  float* op = out + t * DIM;
  const float* bp1 = b2S + e1 * DIM;
  const float* bp2 = b2S + e2 * DIM;
#pragma unroll
  for (int k = 0; k < 12; k++) {
    int n = k * 64 + lane;
    op[n] = bf16_to_f32(y1[n]) + bf16_to_f32(y2[n]) + cg.x * bp1[n] + cg.y * bp2[n];
  }
}

// ---------- bf16 MFMA GEMM, double-buffered single-barrier K-loop ----------
// MODE 0: dense. outB = bf16(acc + bias[col])                                  (GEMM1)
// MODE 1: row-gathered A (token slots) -> g rows (compacted-padded), gelu*gate (GEMM2)
// MODE 2: contiguous A (g rows) -> y rows (compacted-padded), plain bf16 store (GEMM3)
// MODE 1/2: compacted active-tile domain -> XCD swizzle (equal real work/XCD).
// K-loop: loads for tile k+1 issue right after the barrier releasing tile k, so
// the DMA has the whole compute phase to land before its drain at the next
// barrier (vs R6: drain immediately after issue -> full latency exposed 24x).
template <int MODE, int CH>
__launch_bounds__(256)
__global__ void gemm_kernel(const unsigned short* __restrict__ A, const int lda,
                            const unsigned short* __restrict__ Bt, const int ldb,
                            const int K, const int N,
                            const float* __restrict__ bias,
                            const int* __restrict__ idx_tok,
                            const float* __restrict__ gate_sel,
                            const int* __restrict__ cnts,
                            unsigned short* __restrict__ outB, const int ldo) {
  const int lin = blockIdx.y * gridDim.x + blockIdx.x;
  const int nT = gridDim.x;
  const int xcd = lin & 7, t8 = lin >> 3;
  int bn = 0, bm0 = 0;
  int bmLoc = 0, cnt = 1 << 30, segBase = 0, gRow0 = 0;

  if constexpr (MODE == 0) {
    const int perXcd = gridDim.y >> 3;
    const int mi = t8 % CH;
    const int rest = t8 / CH;
    bn = rest % nT;
    const int mc = rest / nT;
    bm0 = (xcd * perXcd + mc * CH + mi) * 128;
  } else {
    const int c0 = cnts[0], c1 = cnts[1], c2 = cnts[2], c3 = cnts[3];
    const int t0 = (c0 + 127) >> 7, t1 = (c1 + 127) >> 7,
              t2 = (c2 + 127) >> 7, t3 = (c3 + 127) >> 7;
    const int p1 = t0, p2 = p1 + t1, p3 = p2 + t2, tot = p3 + t3;
    const int perXcd = (tot + 7) >> 3;  // equal share of ACTIVE tiles per XCD
    bn = t8 % nT;
    const int mloc = t8 / nT;           // n fastest within XCD -> A-tile L2 reuse
    if (mloc >= perXcd) return;
    const int mIdx = xcd * perXcd + mloc;
    if (mIdx >= tot) return;
    const int seg = (mIdx >= p2) ? ((mIdx >= p3) ? 3 : 2) : ((mIdx >= p1) ? 1 : 0);
    const int pre = (seg == 3) ? p3 : (seg == 2) ? p2 : (seg == 1) ? p1 : 0;
    bmLoc = (mIdx - pre) * 128;
    segBase = seg * CAP;
    gRow0 = mIdx * 128;                 // compacted-padded row base = tileIdx*128
    cnt = (seg == 3) ? c3 : (seg == 2) ? c2 : (seg == 1) ? c1 : c0;
    Bt += (size_t)seg * N * ldb;
    if constexpr (MODE == 1) bias += (size_t)seg * N;
  }

  __shared__ unsigned short As[2][128 * 32];
  __shared__ unsigned short Bs[2][128 * 32];
  __shared__ int idxS[128];
  __shared__ float gateS[128];

  const int tid = threadIdx.x;
  const int w = tid >> 6;
  const int lane = tid & 63;

  if constexpr (MODE == 1) {
    if (tid < 128) {
      int r = bmLoc + tid;
      int cl = (r < cnt) ? r : bmLoc;  // clamp to block's first (valid) row
      idxS[tid] = idx_tok[segBase + cl];
      gateS[tid] = gate_sel[segBase + cl];
    }
    __syncthreads();
  }

  // per-thread staging rows are constant across K
  const int r0 = tid >> 2, r1 = 64 + r0;
  const int gq = (tid & 3) ^ (r0 & 3);  // quad XOR swizzle (r1&3 == r0&3)
  const unsigned short *aP0, *aP1;
  if constexpr (MODE == 0) {
    aP0 = A + (size_t)(bm0 + r0) * lda + gq * 8;
    aP1 = A + (size_t)(bm0 + r1) * lda + gq * 8;
  } else if constexpr (MODE == 1) {
    aP0 = A + (size_t)idxS[r0] * lda + gq * 8;
    aP1 = A + (size_t)idxS[r1] * lda + gq * 8;
  } else {
    aP0 = A + (size_t)(gRow0 + r0) * lda + gq * 8;  // contiguous compacted rows
    aP1 = A + (size_t)(gRow0 + r1) * lda + gq * 8;
  }
  const unsigned short* bP0 = Bt + (size_t)(bn * 128 + r0) * ldb + gq * 8;
  const unsigned short* bP1 = Bt + (size_t)(bn * 128 + r1) * ldb + gq * 8;

#define ISSUE(bufi, kk)                                                                        \
  {                                                                                            \
    char* la0 = (char*)As[bufi] + w * 1024;                                                    \
    char* la1 = (char*)As[bufi] + 4096 + w * 1024;                                             \
    char* lb0 = (char*)Bs[bufi] + w * 1024;                                                    \
    char* lb1 = (char*)Bs[bufi] + 4096 + w * 1024;                                             \
    __builtin_amdgcn_global_load_lds((const __attribute__((address_space(1))) void*)(aP0 + (kk)), \
                                     (__attribute__((address_space(3))) void*)la0, 16, 0, 0);  \
    __builtin_amdgcn_global_load_lds((const __attribute__((address_space(1))) void*)(aP1 + (kk)), \
                                     (__attribute__((address_space(3))) void*)la1, 16, 0, 0);  \
    __builtin_amdgcn_global_load_lds((const __attribute__((address_space(1))) void*)(bP0 + (kk)), \
                                     (__attribute__((address_space(3))) void*)lb0, 16, 0, 0);  \
    __builtin_amdgcn_global_load_lds((const __attribute__((address_space(1))) void*)(bP1 + (kk)), \
                                     (__attribute__((address_space(3))) void*)lb1, 16, 0, 0);  \
  }

  f32x4 acc[4][4];
#pragma unroll
  for (int i = 0; i < 4; i++)
#pragma unroll
    for (int j = 0; j < 4; j++) acc[i][j] = (f32x4){0.f, 0.f, 0.f, 0.f};

  const int quad = lane >> 4;
  const int m16 = lane & 15;
  const int wm = (w & 1) * 64;
  const int wn = (w >> 1) * 64;
  const int sw = (quad ^ (m16 & 3)) * 16;  // de-swizzle

  ISSUE(0, 0);
  int buf = 0;
  for (int k0 = 0; k0 < K; k0 += 32) {
    __syncthreads();               // drains buf's loads; prev compute reads done
    if (k0 + 32 < K) ISSUE(buf ^ 1, k0 + 32);  // overlap with compute below
    const char* Ab = (const char*)As[buf];
    const char* Bb = (const char*)Bs[buf];
    s16x8 af[4], bf4[4];
#pragma unroll
    for (int i = 0; i < 4; i++)
      af[i] = *(const s16x8*)(Ab + (wm + i * 16 + m16) * 64 + sw);
#pragma unroll
    for (int j = 0; j < 4; j++)
      bf4[j] = *(const s16x8*)(Bb + (wn + j * 16 + m16) * 64 + sw);
#pragma unroll
    for (int i = 0; i < 4; i++)
#pragma unroll
      for (int j = 0; j < 4; j++)
        acc[i][j] = __builtin_amdgcn_mfma_f32_16x16x32_bf16(af[i], bf4[j], acc[i][j], 0, 0, 0);
    buf ^= 1;
  }
#undef ISSUE

#pragma unroll
  for (int i = 0; i < 4; i++) {
    const int rloc = wm + i * 16 + quad * 4;
#pragma unroll
    for (int j = 0; j < 4; j++) {
      const int col = bn * 128 + wn + j * 16 + m16;
      if constexpr (MODE == 0) {
        float bv = bias[col];
#pragma unroll
        for (int r = 0; r < 4; r++)
          outB[(size_t)(bm0 + rloc + r) * ldo + col] = f32_to_bf16(acc[i][j][r] + bv);
      } else if constexpr (MODE == 1) {
        float bv = bias[col];
#pragma unroll
        for (int r = 0; r < 4; r++) {
          if (bmLoc + rloc + r < cnt) {
            float v = acc[i][j][r] + bv;
            float t3 = v + 0.044715f * v * v * v;
            float e2 = exp2f(t3 * 2.302208206984525f);  // e^{2u}, u=sqrt(2/pi)(v+0.044715v^3)
            float rc = __builtin_amdgcn_rcpf(1.0f + e2);
            float g = v - v * rc;
            outB[(size_t)(gRow0 + rloc + r) * ldo + col] = f32_to_bf16(g * gateS[rloc + r]);
          }
        }
      } else {
#pragma unroll
        for (int r = 0; r < 4; r++) {
          if (bmLoc + rloc + r < cnt)
            outB[(size_t)(gRow0 + rloc + r) * ldo + col] = f32_to_bf16(acc[i][j][r]);
        }
      }
    }
  }
}

extern "C" void kernel_launch(void* const* d_in, const int* in_sizes, int n_in,
                              void* d_out, int out_size, void* d_ws, size_t ws_size,
                              hipStream_t stream) {
  (void)in_sizes; (void)n_in; (void)out_size; (void)ws_size;
  const float* x  = (const float*)d_in[0];
  const float* W  = (const float*)d_in[1];
  const float* b  = (const float*)d_in[2];
  const float* Wg = (const float*)d_in[3];
  const float* bg = (const float*)d_in[4];
  const float* W1 = (const float*)d_in[5];
  const float* b1 = (const float*)d_in[6];
  const float* W2 = (const float*)d_in[7];
  const float* b2 = (const float*)d_in[8];
  float* out = (float*)d_out;
  char* ws = (char*)d_ws;

  // workspace layout (bytes); xbf/wt alias the g region (dead before g is written)
  unsigned short* tbf  = (unsigned short*)(ws + 0);          // [16384][768] bf16
  unsigned short* w1t  = (unsigned short*)(ws + 25165824);   // [4][1024][768] bf16
  unsigned short* w2t  = (unsigned short*)(ws + 31457280);   // [4][768][1024] bf16
  float* wfg           = (float*)(ws + 37748736);            // [768][4]
  float* bgp           = (float*)(ws + 37761024);            // [4]
  int2*  rte           = (int2*)(ws + 37761280);             // [16384]
  float2* rtg          = (float2*)(ws + 37892352);           // [16384]
  int*   cnt           = (int*)(ws + 38023424);              // [4]
  int*   idx_tok       = (int*)(ws + 38023680);              // [4][CAP]
  float* gate_sel      = (float*)(ws + 38285824);            // [4][CAP]
  int2*  tok_slot      = (int2*)(ws + 38547968);             // [16384]
  unsigned short* g    = (unsigned short*)(ws + 38679040);   // [<=33152][1024] bf16 (compacted)
  unsigned short* xbf  = (unsigned short*)(ws + 38679040);   // alias: [16384][768]
  unsigned short* wt   = (unsigned short*)(ws + 63844864);   // alias: [768][768]
  unsigned short* y    = (unsigned short*)(ws + 106574336);  // [<=33152][768] bf16 (compacted)
  // end: 157,495,808 < ~198 MB proven available (R2 merged path ran)

  hipMemsetAsync(cnt, 0, NEXP * sizeof(int), stream);
  transpose_bf16_kernel<<<dim3(24, 24, 1), dim3(32, 8), 0, stream>>>(W, wt, 768, 768, 768, 589824);
  transpose_bf16_kernel<<<dim3(32, 24, 4), dim3(32, 8), 0, stream>>>(W1, w1t, 768, 1024, 768, 786432);
  transpose_bf16_kernel<<<dim3(24, 32, 4), dim3(32, 8), 0, stream>>>(W2, w2t, 1024, 768, 1024, 786432);
  wfg_kernel<<<13, 256, 0, stream>>>(W, Wg, b, bg, wfg, bgp);
  router_kernel<<<4096, 256, 0, stream>>>(x, wfg, bgp, rte, rtg, xbf);  // + fused x->bf16
  assign_kernel<<<64, 256, 0, stream>>>(rte, rtg, cnt, idx_tok, gate_sel, tok_slot);

  // GEMM1: t = bf16(x @ W + b)          [dense, 19.3 GF]
  gemm_kernel<0, 8><<<dim3(6, 128), 256, 0, stream>>>(
      xbf, 768, wt, 768, 768, 768, b, nullptr, nullptr, nullptr, tbf, 768);
  // GEMM2: g[row] = bf16(gate * gelu(t[tok] @ W1_e + b1_e))   [gathered, 51.5 GF]
  gemm_kernel<1, 8><<<dim3(8, 264), 256, 0, stream>>>(
      tbf, 768, w1t, 768, 768, 1024, b1, idx_tok, gate_sel, cnt, g, 1024);
  // GEMM3: y[row] = bf16(g[row] @ W2_e)   [write-once, 51.5 GF]
  gemm_kernel<2, 8><<<dim3(6, 264), 256, 0, stream>>>(
      g, 1024, w2t, 1024, 1024, 768, nullptr, nullptr, nullptr, cnt, y, 768);
  // combine: out[t] = y[slot1] + y[slot2] + c1*b2[e1] + c2*b2[e2]
  combine_kernel<<<4096, 256, 0, stream>>>(y, tok_slot, rtg, cnt, b2, out);
}